// Round 1
// baseline (360.969 us; speedup 1.0000x reference)
//
#include <hip/hip_runtime.h>
#include <math.h>

#define DEV static __device__ __forceinline__

typedef float v2 __attribute__((ext_vector_type(2)));

// DPP helpers — all cross-lane traffic is full-rate VALU DPP (no LDS pipe).
template<int CTRL>
DEV float qperm(float x) {
    return __int_as_float(__builtin_amdgcn_mov_dpp(__float_as_int(x), CTRL, 0xF, 0xF, true));
}
DEV float lx1(float v)  { return qperm<0xB1>(v); }  // quad: xor lane bit0 (qubit2)
DEV float lx2(float v)  { return qperm<0x4E>(v); }  // quad: xor lane bit1 (qubit3)
DEV float ror8(float v) { return qperm<0x128>(v); } // row_ror:8 = xor lane bit3 (qubit1)
DEV float rfl(float x)  { return __int_as_float(__builtin_amdgcn_readfirstlane(__float_as_int(x))); }

template<int CTRL>
DEV v2 qpermv(v2 a) { return (v2){qperm<CTRL>(a.x), qperm<CTRL>(a.y)}; }

DEV v2 vswap(v2 a)  { return __builtin_shufflevector(a, a, 1, 0); }
DEV v2 vsplat(float f) { return (v2){f, f}; }
DEV v2 vfma(v2 a, v2 b, v2 c) { return __builtin_elementwise_fma(a, b, c); }

// Rot on local qubit0 (packed): x' = S x + T y ; y' = -conj(T) x + conj(S) y
DEV void rot_q0v(v2& x, v2& y, float Sr, float Tr, float nTr, v2 Sin, v2 Tin) {
    v2 sx = vswap(x), sy = vswap(y);
    v2 nx = x * Sr;
    nx = vfma(sx, Sin, nx);
    nx = vfma(y, vsplat(Tr), nx);
    nx = vfma(sy, Tin, nx);
    v2 ny = y * Sr;
    ny = vfma(sy, vswap(Sin), ny);
    ny = vfma(x, vsplat(nTr), ny);
    ny = vfma(sx, Tin, ny);
    x = nx; y = ny;
}

// Rot on a lane-distributed qubit (packed); p = partner amp (via DPP).
DEV v2 rot_dv(v2 a, v2 p, float Ur, v2 An, float Br, v2 Wn) {
    v2 n = a * Ur;
    n = vfma(vswap(a), An, n);
    n = vfma(p, vsplat(Br), n);
    n = vfma(vswap(p), Wn, n);
    return n;
}

// Cheap sincos in REVOLUTIONS: v_fract + v_sin + v_cos.
DEV void fsincos(float rev, float* s, float* c) {
    float f = __builtin_amdgcn_fractf(rev);
    *s = __builtin_amdgcn_sinf(f);
    *c = __builtin_amdgcn_cosf(f);
}

__global__ __launch_bounds__(256, 2)
void qrnn_kernel(const float* __restrict__ inputs, const float* __restrict__ initial_t,
                 const float* __restrict__ p1, const float* __restrict__ p2,
                 const float* __restrict__ kbw, const float* __restrict__ ksw,
                 const float* __restrict__ w1, const float* __restrict__ cb1,
                 const float* __restrict__ w2, const float* __restrict__ cb2,
                 float* __restrict__ out, int B, int S)
{
    // 8 lanes/slot, ONE element per thread -> B*8 threads = 512 blocks
    // = 2 waves/SIMD so the second wave hides trans/DPP dependency stalls.
    // lane bit0->qubit2, bit1->qubit3, bit3->qubit1; bit2 = slot select.
    const int tid    = blockIdx.x * blockDim.x + threadIdx.x;
    const int lane16 = threadIdx.x & 15;
    const int e      = (tid >> 4) * 2 + ((lane16 >> 2) & 1);
    if (e >= B) return;
    const int sub    = lane16 & 3;
    const bool b1    = ((lane16 >> 3) & 1) != 0;
    const bool b2 = (sub & 1) != 0, b3 = (sub & 2) != 0;
    const float z2f = b2 ? -1.f : 1.f;
    const float z3f = b3 ? -1.f : 1.f;
    const float z1f = b1 ? -1.f : 1.f;
    const float z12 = z1f * z2f, z23 = z2f * z3f;
    const float z123 = z1f * z23;
    const bool is0 = (sub == 0), is1 = (sub == 1);

    // Angles in REVOLUTIONS with -0.5 half-angle folded: stored = -rad/(4*pi).
    const float REVC = -0.07957747154594767f;   // -1/(4*pi)

    // ---- one-time: 16 Rot matrices (input-constant, element-independent)
    float Sr[4], Tr[4], nTr[4];
    v2    Sin[4], Tin[4];
    float Ur[4][3], Br[4][3];
    v2    An[4][3], Wn[4][3];
    const float* PP[2] = { p1, p2 };
#pragma unroll
    for (int aI = 0; aI < 2; ++aI) {
        const float* pp = PP[aI];
#pragma unroll
        for (int l = 0; l < 2; ++l) {
            const int idx = aI*2 + l;
#pragma unroll
            for (int q = 0; q < 4; ++q) {
                float phi = pp[l*12 + q*3 + 0];
                float tht = pp[l*12 + q*3 + 1];
                float omg = pp[l*12 + q*3 + 2];
                float st, ct; sincosf(0.5f*tht, &st, &ct);
                float sA, cA, sB, cB;
                sincosf(0.5f*(phi + omg), &sA, &cA);
                sincosf(0.5f*(phi - omg), &sB, &cB);
                float u00r =  cA*ct, u00i = -sA*ct;
                float u01r = -cB*st, u01i = -sB*st;
                if (q == 0) {
                    Sr[idx] = rfl(u00r); Tr[idx] = rfl(u01r); nTr[idx] = rfl(-u01r);
                    float Si = rfl(u00i), Ti = rfl(u01i);
                    Sin[idx] = (v2){-Si, Si};
                    Tin[idx] = (v2){-Ti, Ti};
                } else {
                    float zq = (q == 1) ? z1f : (q == 2) ? z2f : z3f;
                    Ur[idx][q-1] = rfl(u00r);
                    float Wi = rfl(u01i);
                    Wn[idx][q-1] = (v2){-Wi, Wi};
                    float vAI = zq * u00i;
                    An[idx][q-1] = (v2){-vAI, vAI};
                    Br[idx][q-1] = zq * u01r;
                }
            }
        }
    }

    // ---- KAN cubic coeffs (lane 'sub' = input dim); REVC folded.
    float kQ0[7], kQ1[7], kQ2[7], kQ3[7], kBW[7];
#pragma unroll
    for (int r = 0; r < 7; ++r) {
        float sw0 = ksw[r*16 + sub*4 + 0], sw1 = ksw[r*16 + sub*4 + 1];
        float sw2 = ksw[r*16 + sub*4 + 2], sw3 = ksw[r*16 + sub*4 + 3];
        const float f = REVC / 48.0f;
        kQ0[r] = f * (sw0 + 23.f*sw1 + 23.f*sw2 + sw3);
        kQ1[r] = f * (-3.f*sw0 - 15.f*sw1 + 15.f*sw2 + 3.f*sw3);
        kQ2[r] = f * (3.f*sw0 - 3.f*sw1 - 3.f*sw2 + 3.f*sw3);
        kQ3[r] = f * (-sw0 + 3.f*sw1 - 3.f*sw2 + sw3);
        kBW[r] = REVC * kbw[r*4 + sub];
    }
    const int pr0[3] = {0, 1, 3}, pr1[3] = {4, 2, 6};
    v2 Q0p[3], Q1p[3], Q2p[3], Q3p[3], BWp[3];
#pragma unroll
    for (int j = 0; j < 3; ++j) {
        Q0p[j] = (v2){kQ0[pr0[j]], kQ0[pr1[j]]};
        Q1p[j] = (v2){kQ1[pr0[j]], kQ1[pr1[j]]};
        Q2p[j] = (v2){kQ2[pr0[j]], kQ2[pr1[j]]};
        Q3p[j] = (v2){kQ3[pr0[j]], kQ3[pr1[j]]};
        BWp[j] = (v2){kBW[pr0[j]], kBW[pr1[j]]};
    }

    // ---- per-element state: hidden pairs + inputs
    v2 H04, H12, H36;
    float H5;
    const float4* inp4 = (const float4*)inputs;
    H04 = (v2){REVC*initial_t[e*7+0], REVC*initial_t[e*7+4]};
    H12 = (v2){REVC*initial_t[e*7+1], REVC*initial_t[e*7+2]};
    H36 = (v2){REVC*initial_t[e*7+3], REVC*initial_t[e*7+6]};
    H5  = REVC*initial_t[e*7+5];
    const long BASE = (long)e * S;
    float4 XC = inp4[BASE];

    const float NQPI = -0.7853981633974483f;   // -pi/4
    float XK = 0.f;
    v2 A0, A1;

#pragma unroll 1
    for (int t = 0; t < S; ++t) {
        const int tn = (t + 1 < S) ? t + 1 : S - 1;
        float4 XN = inp4[BASE + tn];

        // ---- fm(hidden) on |0000>: amp = e^{i*2pi*sig}
        {
            float base = H12.x * z1f;
            base = fmaf(H12.y, z2f, base);
            base = fmaf(H36.x, z3f, base);
            base = fmaf(H5,   z12, base);
            base = fmaf(H36.y, z23, base);
            float w = fmaf(H04.y, z1f, H04.x);
            float s0, c0, s1, c1;
            fsincos(base + w, &s0, &c0);
            fsincos(base - w, &s1, &c1);
            A0 = (v2){c0, s0};
            A1 = (v2){c1, s1};
        }

        // ---- ansatz(p1), fm(x), ansatz(p2). Layer-2 CNOT(3,0) folded into
        // fm_x; layer-4 ring folded into measurement Walsh masks.
#pragma unroll
        for (int half = 0; half < 2; ++half) {
#pragma unroll
            for (int li = 0; li < 2; ++li) {
                const int l = half*2 + li;
                rot_q0v(A0, A1, Sr[l], Tr[l], nTr[l], Sin[l], Tin[l]);
                {   // qubit1
                    v2 q0 = qpermv<0x128>(A0), q1 = qpermv<0x128>(A1);
                    A0 = rot_dv(A0, q0, Ur[l][0], An[l][0], Br[l][0], Wn[l][0]);
                    A1 = rot_dv(A1, q1, Ur[l][0], An[l][0], Br[l][0], Wn[l][0]);
                }
                {   // qubit2
                    v2 q0 = qpermv<0xB1>(A0), q1 = qpermv<0xB1>(A1);
                    A0 = rot_dv(A0, q0, Ur[l][1], An[l][1], Br[l][1], Wn[l][1]);
                    A1 = rot_dv(A1, q1, Ur[l][1], An[l][1], Br[l][1], Wn[l][1]);
                }
                {   // qubit3
                    v2 q0 = qpermv<0x4E>(A0), q1 = qpermv<0x4E>(A1);
                    A0 = rot_dv(A0, q0, Ur[l][2], An[l][2], Br[l][2], Wn[l][2]);
                    A1 = rot_dv(A1, q1, Ur[l][2], An[l][2], Br[l][2], Wn[l][2]);
                }
                if (l < 3) {
                    // CNOT(0,1)
                    A1 = qpermv<0x128>(A1);
                    // CNOT(1,2) o CNOT(2,3): b1=0 -> [0,3,2,1]; b1=1 -> [1,2,3,0]
                    float vA, vB;
                    vA = qperm<0x6C>(A0.x); vB = qperm<0x39>(A0.x); A0.x = b1 ? vB : vA;
                    vA = qperm<0x6C>(A0.y); vB = qperm<0x39>(A0.y); A0.y = b1 ? vB : vA;
                    vA = qperm<0x6C>(A1.x); vB = qperm<0x39>(A1.x); A1.x = b1 ? vB : vA;
                    vA = qperm<0x6C>(A1.y); vB = qperm<0x39>(A1.y); A1.y = b1 ? vB : vA;
                    // CNOT(3,0): layers 1,3 only (layer 2's folded into fm_x)
                    if (li == 0) {
                        v2 t0 = b3 ? A1 : A0;
                        v2 t1 = b3 ? A0 : A1;
                        A0 = t0; A1 = t1;
                    }
                }
            }
            if (half == 0) {
                // ---- fm(x_embed): H^{x4} (unscaled) + diag phase (revolutions)
                float hx0 = REVC*XC.x, hx1 = REVC*XC.y;
                float hx2 = REVC*XC.z, hx3 = REVC*XC.w;
                float u0 = fmaf(4.f, hx0, 1.f);
                float u1 = fmaf(4.f, hx1, 1.f);
                float u2 = fmaf(4.f, hx2, 1.f);
                float u3 = fmaf(4.f, hx3, 1.f);
                float he4 = NQPI * (u0*u1);
                float he5 = NQPI * (u1*u2);
                float he6 = NQPI * (u2*u3);

                // H q0 + folded layer-2 CNOT(3,0): diff scaled by z3f
                v2 n0 = A0 + A1;
                v2 n1 = (A0 - A1) * z3f;
                A0 = n0; A1 = n1;
                { v2 q0 = qpermv<0x128>(A0), q1 = qpermv<0x128>(A1);
                  A0 = vfma(A0, vsplat(z1f), q0);
                  A1 = vfma(A1, vsplat(z1f), q1); }
                { v2 q0 = qpermv<0xB1>(A0), q1 = qpermv<0xB1>(A1);
                  A0 = vfma(A0, vsplat(z2f), q0);
                  A1 = vfma(A1, vsplat(z2f), q1); }
                { v2 q0 = qpermv<0x4E>(A0), q1 = qpermv<0x4E>(A1);
                  A0 = vfma(A0, vsplat(z3f), q0);
                  A1 = vfma(A1, vsplat(z3f), q1); }
                float base = hx1 * z1f;
                base = fmaf(hx2, z2f, base);
                base = fmaf(hx3, z3f, base);
                base = fmaf(he5, z12, base);
                base = fmaf(he6, z23, base);
                float w = fmaf(he4, z1f, hx0);
                float s0, c0, s1, c1;
                fsincos(base + w, &s0, &c0);
                fsincos(base - w, &s1, &c1);
                v2 sn0 = (v2){-s0, s0};
                v2 sn1 = (v2){-s1, s1};
                A0 = vfma(vswap(A0), sn0, A0 * c0);
                A1 = vfma(vswap(A1), sn1, A1 * c1);
            }
        }

        // ---- measurement (layer-4 ring folded into Walsh masks; probs x256)
        {
            v2 m0 = A0 * A0, m1 = A1 * A1;
            float pa = m0.x + m0.y;
            float pb = m1.x + m1.y;
            float s  = pa + pb;
            float dl = pa - pb;
            float u0m = z1f * dl;
            float r3 = u0m + ror8(u0m);
            float rA = r3 + lx1(r3); rA += lx2(rA);       // ev1 everywhere
            float rB = r3 - lx1(r3);
            float rC = fmaf(z2f, lx2(rB), rB);            // sub2->ev2, sub3->ev3
            float vy = z123 * s;
            vy += ror8(vy); vy += lx1(vy); vy += lx2(vy); // ev0 everywhere
            float pre = is0 ? vy : (is1 ? rA : rC);
            XK = pre * (1.0f/256.0f);
        }

        // ---- KAN (packed pairs): lane sub = input dim; quad-reduce sums dims
        {
            float xk = XK;
            float eneg = __builtin_amdgcn_exp2f(xk * -1.44269504088896f);
            float silu = xk * __builtin_amdgcn_rcpf(1.0f + eneg);
            v2 xs = vsplat(xk), ss = vsplat(silu);
            v2 op[3];
#pragma unroll
            for (int k = 0; k < 3; ++k) {
                v2 o = vfma(Q3p[k], xs, Q2p[k]);
                o = vfma(o, xs, Q1p[k]);
                o = vfma(o, xs, Q0p[k]);
                o = vfma(BWp[k], ss, o);
                o = o + (v2){lx1(o.x), lx1(o.y)};
                o = o + (v2){lx2(o.x), lx2(o.y)};
                op[k] = o;
            }
            {   // scalar r=5
                float o = fmaf(kQ3[5], xk, kQ2[5]);
                o = fmaf(o, xk, kQ1[5]);
                o = fmaf(o, xk, kQ0[5]);
                o = fmaf(kBW[5], silu, o);
                o += lx1(o); o += lx2(o);
                H5 = o;
            }
            H04 = op[0]; H12 = op[1]; H36 = op[2];
            XC = XN;
        }
    }

    // ---- classifier head: quad lanes hold ev0..ev3 per element
    {
        float xk  = XK;
        float ev1 = qperm<0x55>(xk);
        float ev2 = qperm<0xAA>(xk);
        float ev3 = qperm<0xFF>(xk);
        if (sub == 0 && !b1) {
            float acc = cb2[0];
#pragma unroll
            for (int i = 0; i < 16; ++i) {
                float h = cb1[i] + w1[i*4+0]*xk + w1[i*4+1]*ev1
                        + w1[i*4+2]*ev2 + w1[i*4+3]*ev3;
                h = fmaxf(h, 0.0f);
                acc += w2[i]*h;
            }
            out[e] = acc;
        }
    }
}

extern "C" void kernel_launch(void* const* d_in, const int* in_sizes, int n_in,
                              void* d_out, int out_size, void* d_ws, size_t ws_size,
                              hipStream_t stream) {
    const float* inputs    = (const float*)d_in[0];
    const float* initial_t = (const float*)d_in[1];
    const float* p1        = (const float*)d_in[2];
    const float* p2        = (const float*)d_in[3];
    const float* kbw       = (const float*)d_in[4];
    const float* ksw       = (const float*)d_in[5];
    const float* w1        = (const float*)d_in[6];
    const float* cb1       = (const float*)d_in[7];
    const float* w2        = (const float*)d_in[8];
    const float* cb2       = (const float*)d_in[9];

    const int B = in_sizes[1] / 7;            // 16384
    const int S = in_sizes[0] / (B * 4);      // 256

    const int threads = B * 8;                // 8 lanes/slot, 1 element/thread
    const int block = 256;
    const int grid = (threads + block - 1) / block;   // 512 blocks -> 2 waves/SIMD

    qrnn_kernel<<<grid, block, 0, stream>>>(inputs, initial_t, p1, p2, kbw, ksw,
                                            w1, cb1, w2, cb2, (float*)d_out, B, S);
}

// Round 2
// 337.768 us; speedup vs baseline: 1.0687x; 1.0687x over previous
//
#include <hip/hip_runtime.h>
#include <math.h>

#define DEV static __device__ __forceinline__

typedef float v2 __attribute__((ext_vector_type(2)));

// DPP helpers — all cross-lane traffic is full-rate VALU DPP (no LDS pipe).
template<int CTRL>
DEV float qperm(float x) {
    return __int_as_float(__builtin_amdgcn_mov_dpp(__float_as_int(x), CTRL, 0xF, 0xF, true));
}
DEV float lx1(float v)  { return qperm<0xB1>(v); }   // xor lane bit0 (stored q2)
DEV float lx2(float v)  { return qperm<0x4E>(v); }   // xor lane bit1 (stored q3)
DEV float x3f_(float v) { return qperm<0x1B>(v); }   // xor lane bits 0&1
DEV float ror8(float v) { return qperm<0x128>(v); }  // xor lane bit3 (stored q1)
DEV float rfl(float x)  { return __int_as_float(__builtin_amdgcn_readfirstlane(__float_as_int(x))); }

DEV v2 ror8v(v2 a){ return (v2){ror8(a.x), ror8(a.y)}; }
DEV v2 lx1v(v2 a) { return (v2){lx1(a.x), lx1(a.y)}; }
DEV v2 lx2v(v2 a) { return (v2){lx2(a.x), lx2(a.y)}; }
DEV v2 x3v(v2 a)  { return (v2){x3f_(a.x), x3f_(a.y)}; }
DEV v2 r8lx1v(v2 a){ return (v2){ror8(lx1(a.x)), ror8(lx1(a.y))}; }
DEV v2 r8lx2v(v2 a){ return (v2){ror8(lx2(a.x)), ror8(lx2(a.y))}; }

DEV v2 vswap(v2 a)  { return __builtin_shufflevector(a, a, 1, 0); }
DEV v2 vsplat(float f) { return (v2){f, f}; }
DEV v2 vfma(v2 a, v2 b, v2 c) { return __builtin_elementwise_fma(a, b, c); }

// generalized masked-rot pair update: n = A*dr + swap(A)*di + P*orr + swap(P)*oi
// (sigma sign functionals are pre-folded into dr/di/orr/oi per lane; A1-side
//  sign flips are passed as negated operands -> free VOP3 source modifiers)
DEV v2 gup(v2 A, v2 P, float dr, v2 di, float orr, v2 oi) {
    v2 n = A * dr;
    n = vfma(vswap(A), di, n);
    n = vfma(P, vsplat(orr), n);
    n = vfma(vswap(P), oi, n);
    return n;
}

// Cheap sincos in REVOLUTIONS: v_fract + v_sin + v_cos.
DEV void fsincos(float rev, float* s, float* c) {
    float f = __builtin_amdgcn_fractf(rev);
    *s = __builtin_amdgcn_sinf(f);
    *c = __builtin_amdgcn_cosf(f);
}

__global__ __launch_bounds__(256, 1)
void qrnn_kernel(const float* __restrict__ inputs, const float* __restrict__ initial_t,
                 const float* __restrict__ p1, const float* __restrict__ p2,
                 const float* __restrict__ kbw, const float* __restrict__ ksw,
                 const float* __restrict__ w1, const float* __restrict__ cb1,
                 const float* __restrict__ w2, const float* __restrict__ cb2,
                 float* __restrict__ out, int B, int S)
{
    // 8 lanes/slot, TWO elements per thread (eA, eB=eA+B/2) for 2-way ILP.
    // lane bit0->stored q2, bit1->stored q3, bit3->stored q1; bit2 = slot select.
    // CNOT rings are never applied: they are delayed as a pending linear frame Q
    // and folded into later gates' partner masks + Walsh sign constants.
    const int tid    = blockIdx.x * blockDim.x + threadIdx.x;
    const int lane16 = threadIdx.x & 15;
    const int eA     = (tid >> 4) * 2 + ((lane16 >> 2) & 1);
    const int halfB  = B >> 1;
    if (eA >= halfB) return;
    const int eB     = eA + halfB;
    const int sub    = lane16 & 3;
    const bool b1    = ((lane16 >> 3) & 1) != 0;
    const bool b2 = (sub & 1) != 0, b3 = (sub & 2) != 0;
    const float z2f = b2 ? -1.f : 1.f;
    const float z3f = b3 ? -1.f : 1.f;
    const float z1f = b1 ? -1.f : 1.f;
    const float z12 = z1f * z2f, z23 = z2f * z3f, z13 = z1f * z3f;
    const float z123 = z1f * z23;
    const bool is0 = (sub == 0), is1 = (sub == 1), is2 = (sub == 2);

    // Angles in REVOLUTIONS with -0.5 half-angle folded: stored = -rad/(4*pi).
    const float REVC = -0.07957747154594767f;   // -1/(4*pi)

    // ---- one-time: 16 base Rot matrices (input-constant)
    float u00r[4][4], u00i[4][4], u01r[4][4], u01i[4][4];
    const float* PP[2] = { p1, p2 };
#pragma unroll
    for (int aI = 0; aI < 2; ++aI) {
        const float* pp = PP[aI];
#pragma unroll
        for (int l = 0; l < 2; ++l) {
            const int idx = aI*2 + l;
#pragma unroll
            for (int q = 0; q < 4; ++q) {
                float phi = pp[l*12 + q*3 + 0];
                float tht = pp[l*12 + q*3 + 1];
                float omg = pp[l*12 + q*3 + 2];
                float st, ct; sincosf(0.5f*tht, &st, &ct);
                float sA, cA, sB, cB;
                sincosf(0.5f*(phi + omg), &sA, &cA);
                sincosf(0.5f*(phi - omg), &sB, &cB);
                u00r[idx][q] = rfl( cA*ct); u00i[idx][q] = rfl(-sA*ct);
                u01r[idx][q] = rfl(-cB*st); u01i[idx][q] = rfl(-sB*st);
            }
        }
    }

    // idx0: ansatz1 layer1, frame I (identical to verified baseline gates)
    const float Sr0 = u00r[0][0], Tr0 = u01r[0][0];
    const v2 Sin0 = (v2){-u00i[0][0], u00i[0][0]};
    const v2 Tin0 = (v2){-u01i[0][0], u01i[0][0]};
    float U0r[3], B0r[3]; v2 A0n[3], W0n[3];
    {
        const float zq3[3] = { z1f, z2f, z3f };
#pragma unroll
        for (int q = 1; q < 4; ++q) {
            float z = zq3[q-1];
            U0r[q-1] = u00r[0][q];
            A0n[q-1] = (v2){-z*u00i[0][q], z*u00i[0][q]};
            B0r[q-1] = z*u01r[0][q];
            W0n[q-1] = (v2){-u01i[0][q], u01i[0][q]};
        }
    }
    // idx1: V = H*U (unscaled, det -1: [[a,b],[b~,-a~]]), frame Q1 = R.
    // masks: q0:{n0,n1} q1:{n1,n2} q2:{n2,n3} q3:{n0,n1,n3}
    // sigma: {z123, n0*z1, n0*z12, n0*z123}  (det-1 fold: sigma on diag-REAL & off-IMAG)
    float d1r[4], o1r[4]; v2 d1i[4], o1i[4];
    {
        const float zf1[4] = { z123, z1f, z12, z123 };
#pragma unroll
        for (int q = 0; q < 4; ++q) {
            float ar = u00r[1][q] - u01r[1][q];
            float ai = u00i[1][q] + u01i[1][q];
            float br = u00r[1][q] + u01r[1][q];
            float bi = u01i[1][q] - u00i[1][q];
            float z = zf1[q];
            d1r[q] = z*ar;
            d1i[q] = (v2){-ai, ai};
            o1r[q] = br;
            o1i[q] = (v2){-z*bi, z*bi};
        }
    }
    // idx2: ansatz2 layer1 (det +1), frame Q2. masks: q0:{n0} q1:{n0,n2} q2:{n0,n3} q3:{n1}
    // sigma: {n0*z23, z2, z3, z1}  (det+1 fold: sigma on diag-IMAG & off-REAL)
    float s2r[4], t2r[4]; v2 s2i[4], t2i[4];
    {
        const float zf2[4] = { z23, z2f, z3f, z1f };
#pragma unroll
        for (int q = 0; q < 4; ++q) {
            float z = zf2[q];
            s2r[q] = u00r[2][q];
            s2i[q] = (v2){-z*u00i[2][q], z*u00i[2][q]};
            t2r[q] = z*u01r[2][q];
            t2i[q] = (v2){-u01i[2][q], u01i[2][q]};
        }
    }
    // idx3: ansatz2 layer2, frame Q3. masks: q0:{n2} q1:{n2,n3} q2:{n0,n1,n3} q3:{n1,n2}
    // sigma: {z123, n0*z3, n0, n0*z1}
    float s3r[4], t3r[4]; v2 s3i[4], t3i[4];
    {
        const float zf3[4] = { z123, z3f, 1.0f, z1f };
#pragma unroll
        for (int q = 0; q < 4; ++q) {
            float z = zf3[q];
            s3r[q] = u00r[3][q];
            s3i[q] = (v2){-z*u00i[3][q], z*u00i[3][q]};
            t3r[q] = z*u01r[3][q];
            t3i[q] = (v2){-u01i[3][q], u01i[3][q]};
        }
    }

    // ---- KAN cubic coeffs (lane 'sub' = input dim); REVC folded.
    float kQ0[7], kQ1[7], kQ2[7], kQ3[7], kBW[7];
#pragma unroll
    for (int r = 0; r < 7; ++r) {
        float sw0 = ksw[r*16 + sub*4 + 0], sw1 = ksw[r*16 + sub*4 + 1];
        float sw2 = ksw[r*16 + sub*4 + 2], sw3 = ksw[r*16 + sub*4 + 3];
        const float f = REVC / 48.0f;
        kQ0[r] = f * (sw0 + 23.f*sw1 + 23.f*sw2 + sw3);
        kQ1[r] = f * (-3.f*sw0 - 15.f*sw1 + 15.f*sw2 + 3.f*sw3);
        kQ2[r] = f * (3.f*sw0 - 3.f*sw1 - 3.f*sw2 + 3.f*sw3);
        kQ3[r] = f * (-sw0 + 3.f*sw1 - 3.f*sw2 + sw3);
        kBW[r] = REVC * kbw[r*4 + sub];
    }
    const int pr0[3] = {0, 1, 3}, pr1[3] = {4, 2, 6};
    v2 Q0p[3], Q1p[3], Q2p[3], Q3p[3], BWp[3];
#pragma unroll
    for (int j = 0; j < 3; ++j) {
        Q0p[j] = (v2){kQ0[pr0[j]], kQ0[pr1[j]]};
        Q1p[j] = (v2){kQ1[pr0[j]], kQ1[pr1[j]]};
        Q2p[j] = (v2){kQ2[pr0[j]], kQ2[pr1[j]]};
        Q3p[j] = (v2){kQ3[pr0[j]], kQ3[pr1[j]]};
        BWp[j] = (v2){kBW[pr0[j]], kBW[pr1[j]]};
    }

    // measurement: residual Walsh-strip + /256 folded into one per-lane scale
    // EV0=sum z1z3*dl, EV1=sum z1z2*dl, EV2=sum z1z2*s, EV3=sum z2*dl
    const float SCL = (is0 ? z13 : (is1 ? z12 : (is2 ? z12 : z2f))) * (1.0f/256.0f);

    // ---- per-element state (x2): hidden pairs + inputs
    const int EE[2] = { eA, eB };
    v2 H04[2], H12[2], H36[2];
    float H5[2];
    long BASE[2];
    float4 XC[2];
    const float4* inp4 = (const float4*)inputs;
#pragma unroll
    for (int j = 0; j < 2; ++j) {
        const int e = EE[j];
        H04[j] = (v2){REVC*initial_t[e*7+0], REVC*initial_t[e*7+4]};
        H12[j] = (v2){REVC*initial_t[e*7+1], REVC*initial_t[e*7+2]};
        H36[j] = (v2){REVC*initial_t[e*7+3], REVC*initial_t[e*7+6]};
        H5[j]  = REVC*initial_t[e*7+5];
        BASE[j] = (long)e * S;
        XC[j] = inp4[BASE[j]];
    }

    const float NQPI = -0.7853981633974483f;   // -pi/4
    float XK[2] = {0.f, 0.f};
    v2 A0[2], A1[2];

#pragma unroll 1
    for (int t = 0; t < S; ++t) {
        const int tn = (t + 1 < S) ? t + 1 : S - 1;
        float4 XN[2];
#pragma unroll
        for (int j = 0; j < 2; ++j) XN[j] = inp4[BASE[j] + tn];

        // ---- fm(hidden) on |0000>: amp = e^{i*2pi*sig}  (frame I)
#pragma unroll
        for (int j = 0; j < 2; ++j) {
            float base = H12[j].x * z1f;
            base = fmaf(H12[j].y, z2f, base);
            base = fmaf(H36[j].x, z3f, base);
            base = fmaf(H5[j],   z12, base);
            base = fmaf(H36[j].y, z23, base);
            float w = fmaf(H04[j].y, z1f, H04[j].x);
            float s0, c0, s1, c1;
            fsincos(base + w, &s0, &c0);
            fsincos(base - w, &s1, &c1);
            A0[j] = (v2){c0, s0};
            A1[j] = (v2){c1, s1};
        }

        // ======== L0: ansatz1 layer1 (frame I). Ring R1 delayed. ========
#pragma unroll
        for (int j = 0; j < 2; ++j) {   // q0: local pair
            v2 n0 = gup(A0[j], A1[j], Sr0,  Sin0,  Tr0, Tin0);
            v2 n1 = gup(A1[j], A0[j], Sr0, -Sin0, -Tr0, Tin0);
            A0[j] = n0; A1[j] = n1;
        }
#pragma unroll
        for (int j = 0; j < 2; ++j) {   // q1: ror8, sigma z1
            A0[j] = gup(A0[j], ror8v(A0[j]), U0r[0], A0n[0], B0r[0], W0n[0]);
            A1[j] = gup(A1[j], ror8v(A1[j]), U0r[0], A0n[0], B0r[0], W0n[0]);
        }
#pragma unroll
        for (int j = 0; j < 2; ++j) {   // q2: lx1, sigma z2
            A0[j] = gup(A0[j], lx1v(A0[j]), U0r[1], A0n[1], B0r[1], W0n[1]);
            A1[j] = gup(A1[j], lx1v(A1[j]), U0r[1], A0n[1], B0r[1], W0n[1]);
        }
#pragma unroll
        for (int j = 0; j < 2; ++j) {   // q3: lx2, sigma z3
            A0[j] = gup(A0[j], lx2v(A0[j]), U0r[2], A0n[2], B0r[2], W0n[2]);
            A1[j] = gup(A1[j], lx2v(A1[j]), U0r[2], A0n[2], B0r[2], W0n[2]);
        }

        // ======== L1': H-folded ansatz1 layer2 (det -1), frame Q1 ========
#pragma unroll
        for (int j = 0; j < 2; ++j) {   // g0: mask {n0,n1}: partner=ror8(other); sigma z123 (same both)
            v2 p0 = ror8v(A1[j]), p1 = ror8v(A0[j]);
            v2 n0 = gup(A0[j], p0, d1r[0], d1i[0], o1r[0], o1i[0]);
            v2 n1 = gup(A1[j], p1, d1r[0], d1i[0], o1r[0], o1i[0]);
            A0[j] = n0; A1[j] = n1;
        }
#pragma unroll
        for (int j = 0; j < 2; ++j) {   // g1: mask {n1,n2}: same-reg chain; sigma n0*z1 -> A1 negs (dr,oi)
            A0[j] = gup(A0[j], r8lx1v(A0[j]),  d1r[1], d1i[1], o1r[1],  o1i[1]);
            A1[j] = gup(A1[j], r8lx1v(A1[j]), -d1r[1], d1i[1], o1r[1], -o1i[1]);
        }
#pragma unroll
        for (int j = 0; j < 2; ++j) {   // g2: mask {n2,n3}: quad xor3; sigma n0*z12
            A0[j] = gup(A0[j], x3v(A0[j]),  d1r[2], d1i[2], o1r[2],  o1i[2]);
            A1[j] = gup(A1[j], x3v(A1[j]), -d1r[2], d1i[2], o1r[2], -o1i[2]);
        }
#pragma unroll
        for (int j = 0; j < 2; ++j) {   // g3: mask {n0,n1,n3}: partner=ror8(lx2(other)); sigma n0*z123
            v2 p0 = r8lx2v(A1[j]), p1 = r8lx2v(A0[j]);
            v2 n0 = gup(A0[j], p0,  d1r[3], d1i[3], o1r[3],  o1i[3]);
            v2 n1 = gup(A1[j], p1, -d1r[3], d1i[3], o1r[3], -o1i[3]);
            A0[j] = n0; A1[j] = n1;
        }

        // ======== Phase_x (diag), frame Q2: Z0->n0*z23, Z1->z2, Z2->z3, Z3->z1,
        //          Z0Z1->n0*z3, Z1Z2->z23, Z2Z3->z13 ========
#pragma unroll
        for (int j = 0; j < 2; ++j) {
            float hx0 = REVC*XC[j].x, hx1 = REVC*XC[j].y;
            float hx2 = REVC*XC[j].z, hx3 = REVC*XC[j].w;
            float u0 = fmaf(4.f, hx0, 1.f);
            float u1 = fmaf(4.f, hx1, 1.f);
            float u2 = fmaf(4.f, hx2, 1.f);
            float u3 = fmaf(4.f, hx3, 1.f);
            float he4 = NQPI * (u0*u1);
            float he5 = NQPI * (u1*u2);
            float he6 = NQPI * (u2*u3);

            float base = hx1 * z2f;
            base = fmaf(hx2, z3f, base);
            base = fmaf(hx3, z1f, base);
            base = fmaf(he5, z23, base);
            base = fmaf(he6, z13, base);
            float w = fmaf(he4, z3f, hx0 * z23);
            float s0, c0, s1, c1;
            fsincos(base + w, &s0, &c0);
            fsincos(base - w, &s1, &c1);
            v2 sn0 = (v2){-s0, s0};
            v2 sn1 = (v2){-s1, s1};
            A0[j] = vfma(vswap(A0[j]), sn0, A0[j] * c0);
            A1[j] = vfma(vswap(A1[j]), sn1, A1[j] * c1);
        }

        // ======== L2: ansatz2 layer1 (det +1), frame Q2 ========
#pragma unroll
        for (int j = 0; j < 2; ++j) {   // g0: mask {n0} local; sigma n0*z23 -> A1 negs (di,orr)
            v2 n0 = gup(A0[j], A1[j], s2r[0],  s2i[0],  t2r[0], t2i[0]);
            v2 n1 = gup(A1[j], A0[j], s2r[0], -s2i[0], -t2r[0], t2i[0]);
            A0[j] = n0; A1[j] = n1;
        }
#pragma unroll
        for (int j = 0; j < 2; ++j) {   // g1: mask {n0,n2}: partner=lx1(other); sigma z2 (same)
            v2 p0 = lx1v(A1[j]), p1 = lx1v(A0[j]);
            v2 n0 = gup(A0[j], p0, s2r[1], s2i[1], t2r[1], t2i[1]);
            v2 n1 = gup(A1[j], p1, s2r[1], s2i[1], t2r[1], t2i[1]);
            A0[j] = n0; A1[j] = n1;
        }
#pragma unroll
        for (int j = 0; j < 2; ++j) {   // g2: mask {n0,n3}: partner=lx2(other); sigma z3 (same)
            v2 p0 = lx2v(A1[j]), p1 = lx2v(A0[j]);
            v2 n0 = gup(A0[j], p0, s2r[2], s2i[2], t2r[2], t2i[2]);
            v2 n1 = gup(A1[j], p1, s2r[2], s2i[2], t2r[2], t2i[2]);
            A0[j] = n0; A1[j] = n1;
        }
#pragma unroll
        for (int j = 0; j < 2; ++j) {   // g3: mask {n1}: ror8 same; sigma z1 (same)
            A0[j] = gup(A0[j], ror8v(A0[j]), s2r[3], s2i[3], t2r[3], t2i[3]);
            A1[j] = gup(A1[j], ror8v(A1[j]), s2r[3], s2i[3], t2r[3], t2i[3]);
        }

        // ======== L3: ansatz2 layer2 (det +1), frame Q3 ========
#pragma unroll
        for (int j = 0; j < 2; ++j) {   // g0: mask {n2}: lx1 same; sigma z123 (same)
            A0[j] = gup(A0[j], lx1v(A0[j]), s3r[0], s3i[0], t3r[0], t3i[0]);
            A1[j] = gup(A1[j], lx1v(A1[j]), s3r[0], s3i[0], t3r[0], t3i[0]);
        }
#pragma unroll
        for (int j = 0; j < 2; ++j) {   // g1: mask {n2,n3}: quad xor3; sigma n0*z3 -> A1 negs
            A0[j] = gup(A0[j], x3v(A0[j]),  s3r[1],  s3i[1],  t3r[1], t3i[1]);
            A1[j] = gup(A1[j], x3v(A1[j]),  s3r[1], -s3i[1], -t3r[1], t3i[1]);
        }
#pragma unroll
        for (int j = 0; j < 2; ++j) {   // g2: mask {n0,n1,n3}: partner=ror8(lx2(other)); sigma n0
            v2 p0 = r8lx2v(A1[j]), p1 = r8lx2v(A0[j]);
            v2 n0 = gup(A0[j], p0, s3r[2],  s3i[2],  t3r[2], t3i[2]);
            v2 n1 = gup(A1[j], p1, s3r[2], -s3i[2], -t3r[2], t3i[2]);
            A0[j] = n0; A1[j] = n1;
        }
#pragma unroll
        for (int j = 0; j < 2; ++j) {   // g3: mask {n1,n2}: ror8(lx1(same)); sigma n0*z1 -> A1 negs
            A0[j] = gup(A0[j], r8lx1v(A0[j]), s3r[3],  s3i[3],  t3r[3], t3i[3]);
            A1[j] = gup(A1[j], r8lx1v(A1[j]), s3r[3], -s3i[3], -t3r[3], t3i[3]);
        }

        // ---- measurement, frame Q4 folded into Walsh butterflies (probs x256)
#pragma unroll
        for (int j = 0; j < 2; ++j) {
            v2 m0 = A0[j] * A0[j], m1 = A1[j] * A1[j];
            float pa = m0.x + m0.y;
            float pb = m1.x + m1.y;
            float s  = pa + pb;
            float dl = pa - pb;
            float rd = ror8(dl);
            float tA = dl - rd;                    // antisym b3
            float vA = dl + rd;                    // sym b3
            float t1 = tA - lx1(tA); t1 += lx2(t1);  // z1z2*EV1
            float t0 = tA + lx1(tA); t0 -= lx2(t0);  // z1z3*EV0
            float v1 = vA - lx1(vA); v1 += lx2(v1);  // z2*EV3
            float wA = s - ror8(s);
            float w1 = wA - lx1(wA); w1 += lx2(w1);  // z1z2*EV2
            float pre = is0 ? t0 : (is1 ? t1 : (is2 ? w1 : v1));
            XK[j] = pre * SCL;
        }

        // ---- KAN (packed pairs): lane sub = input dim; quad-reduce sums dims
#pragma unroll
        for (int j = 0; j < 2; ++j) {
            float xk = XK[j];
            float eneg = __builtin_amdgcn_exp2f(xk * -1.44269504088896f);
            float silu = xk * __builtin_amdgcn_rcpf(1.0f + eneg);
            v2 xs = vsplat(xk), ss = vsplat(silu);
            v2 op[3];
#pragma unroll
            for (int k = 0; k < 3; ++k) {
                v2 o = vfma(Q3p[k], xs, Q2p[k]);
                o = vfma(o, xs, Q1p[k]);
                o = vfma(o, xs, Q0p[k]);
                o = vfma(BWp[k], ss, o);
                o = o + (v2){lx1(o.x), lx1(o.y)};
                o = o + (v2){lx2(o.x), lx2(o.y)};
                op[k] = o;
            }
            {   // scalar r=5
                float o = fmaf(kQ3[5], xk, kQ2[5]);
                o = fmaf(o, xk, kQ1[5]);
                o = fmaf(o, xk, kQ0[5]);
                o = fmaf(kBW[5], silu, o);
                o += lx1(o); o += lx2(o);
                H5[j] = o;
            }
            H04[j] = op[0]; H12[j] = op[1]; H36[j] = op[2];
            XC[j] = XN[j];
        }
    }

    // ---- classifier head: quad lanes hold ev0..ev3 per element
#pragma unroll
    for (int j = 0; j < 2; ++j) {
        float xk  = XK[j];
        float ev1 = qperm<0x55>(xk);
        float ev2 = qperm<0xAA>(xk);
        float ev3 = qperm<0xFF>(xk);
        if (sub == 0 && !b1) {
            float acc = cb2[0];
#pragma unroll
            for (int i = 0; i < 16; ++i) {
                float h = cb1[i] + w1[i*4+0]*xk + w1[i*4+1]*ev1
                        + w1[i*4+2]*ev2 + w1[i*4+3]*ev3;
                h = fmaxf(h, 0.0f);
                acc += w2[i]*h;
            }
            out[EE[j]] = acc;
        }
    }
}

extern "C" void kernel_launch(void* const* d_in, const int* in_sizes, int n_in,
                              void* d_out, int out_size, void* d_ws, size_t ws_size,
                              hipStream_t stream) {
    const float* inputs    = (const float*)d_in[0];
    const float* initial_t = (const float*)d_in[1];
    const float* p1        = (const float*)d_in[2];
    const float* p2        = (const float*)d_in[3];
    const float* kbw       = (const float*)d_in[4];
    const float* ksw       = (const float*)d_in[5];
    const float* w1        = (const float*)d_in[6];
    const float* cb1       = (const float*)d_in[7];
    const float* w2        = (const float*)d_in[8];
    const float* cb2       = (const float*)d_in[9];

    const int B = in_sizes[1] / 7;            // 16384
    const int S = in_sizes[0] / (B * 4);      // 256

    const int threads = (B / 2) * 8;          // 8 lanes/slot, 2 elements/thread
    const int block = 256;
    const int grid = (threads + block - 1) / block;   // 256 blocks -> 1 wave/SIMD

    qrnn_kernel<<<grid, block, 0, stream>>>(inputs, initial_t, p1, p2, kbw, ksw,
                                            w1, cb1, w2, cb2, (float*)d_out, B, S);
}

// Round 3
// 317.676 us; speedup vs baseline: 1.1363x; 1.0632x over previous
//
#include <hip/hip_runtime.h>
#include <math.h>

#define DEV static __device__ __forceinline__

typedef float v2 __attribute__((ext_vector_type(2)));

// DPP helpers — all cross-lane traffic is full-rate VALU DPP (no LDS pipe).
template<int CTRL>
DEV float qperm(float x) {
    return __int_as_float(__builtin_amdgcn_mov_dpp(__float_as_int(x), CTRL, 0xF, 0xF, true));
}
DEV float lx1(float v)  { return qperm<0xB1>(v); }   // xor lane bit0 (stored q2)
DEV float lx2(float v)  { return qperm<0x4E>(v); }   // xor lane bit1 (stored q3)
DEV float x3f_(float v) { return qperm<0x1B>(v); }   // xor lane bits 0&1
DEV float ror8(float v) { return qperm<0x128>(v); }  // xor lane bit3 (stored q1)
DEV float rfl(float x)  { return __int_as_float(__builtin_amdgcn_readfirstlane(__float_as_int(x))); }

DEV v2 ror8v(v2 a){ return (v2){ror8(a.x), ror8(a.y)}; }
DEV v2 lx1v(v2 a) { return (v2){lx1(a.x), lx1(a.y)}; }
DEV v2 lx2v(v2 a) { return (v2){lx2(a.x), lx2(a.y)}; }
DEV v2 x3v(v2 a)  { return (v2){x3f_(a.x), x3f_(a.y)}; }
DEV v2 r8lx1v(v2 a){ return (v2){ror8(lx1(a.x)), ror8(lx1(a.y))}; }
DEV v2 r8lx2v(v2 a){ return (v2){ror8(lx2(a.x)), ror8(lx2(a.y))}; }

DEV v2 vswap(v2 a)  { return __builtin_shufflevector(a, a, 1, 0); }
DEV v2 vsplat(float f) { return (v2){f, f}; }
DEV v2 vfma(v2 a, v2 b, v2 c) { return __builtin_elementwise_fma(a, b, c); }

// generalized masked-rot pair update: n = A*dr + swap(A)*di + P*orr + swap(P)*oi
// (sigma sign functionals are pre-folded into dr/di/orr/oi per lane; A1-side
//  sign flips are passed as negated operands -> free VOP3 source modifiers)
DEV v2 gup(v2 A, v2 P, float dr, v2 di, float orr, v2 oi) {
    v2 n = A * dr;
    n = vfma(vswap(A), di, n);
    n = vfma(P, vsplat(orr), n);
    n = vfma(vswap(P), oi, n);
    return n;
}

// Cheap sincos in REVOLUTIONS: v_fract + v_sin + v_cos.
DEV void fsincos(float rev, float* s, float* c) {
    float f = __builtin_amdgcn_fractf(rev);
    *s = __builtin_amdgcn_sinf(f);
    *c = __builtin_amdgcn_cosf(f);
}

__global__ __launch_bounds__(256, 2)
void qrnn_kernel(const float* __restrict__ inputs, const float* __restrict__ initial_t,
                 const float* __restrict__ p1, const float* __restrict__ p2,
                 const float* __restrict__ kbw, const float* __restrict__ ksw,
                 const float* __restrict__ w1, const float* __restrict__ cb1,
                 const float* __restrict__ w2, const float* __restrict__ cb2,
                 float* __restrict__ out, int B, int S)
{
    // 8 lanes/slot, ONE element per thread -> B*8 threads = 512 blocks
    // = 2 waves/SIMD: second wave fills trans-pipe + DPP-hazard bubbles
    // of the lean (frame-tracked) body, which runs at only ~78% VALUBusy
    // with a single resident wave.
    // lane bit0->stored q2, bit1->stored q3, bit3->stored q1; bit2 = slot select.
    // CNOT rings are never applied: they are delayed as a pending linear frame Q
    // and folded into later gates' partner masks + Walsh sign constants.
    const int tid    = blockIdx.x * blockDim.x + threadIdx.x;
    const int lane16 = threadIdx.x & 15;
    const int e      = (tid >> 4) * 2 + ((lane16 >> 2) & 1);
    if (e >= B) return;
    const int sub    = lane16 & 3;
    const bool b1    = ((lane16 >> 3) & 1) != 0;
    const bool b2 = (sub & 1) != 0, b3 = (sub & 2) != 0;
    const float z2f = b2 ? -1.f : 1.f;
    const float z3f = b3 ? -1.f : 1.f;
    const float z1f = b1 ? -1.f : 1.f;
    const float z12 = z1f * z2f, z23 = z2f * z3f, z13 = z1f * z3f;
    const float z123 = z1f * z23;
    const bool is0 = (sub == 0), is1 = (sub == 1), is2 = (sub == 2);

    // Angles in REVOLUTIONS with -0.5 half-angle folded: stored = -rad/(4*pi).
    const float REVC = -0.07957747154594767f;   // -1/(4*pi)

    // ---- one-time: 16 base Rot matrices (input-constant)
    float u00r[4][4], u00i[4][4], u01r[4][4], u01i[4][4];
    const float* PP[2] = { p1, p2 };
#pragma unroll
    for (int aI = 0; aI < 2; ++aI) {
        const float* pp = PP[aI];
#pragma unroll
        for (int l = 0; l < 2; ++l) {
            const int idx = aI*2 + l;
#pragma unroll
            for (int q = 0; q < 4; ++q) {
                float phi = pp[l*12 + q*3 + 0];
                float tht = pp[l*12 + q*3 + 1];
                float omg = pp[l*12 + q*3 + 2];
                float st, ct; sincosf(0.5f*tht, &st, &ct);
                float sA, cA, sB, cB;
                sincosf(0.5f*(phi + omg), &sA, &cA);
                sincosf(0.5f*(phi - omg), &sB, &cB);
                u00r[idx][q] = rfl( cA*ct); u00i[idx][q] = rfl(-sA*ct);
                u01r[idx][q] = rfl(-cB*st); u01i[idx][q] = rfl(-sB*st);
            }
        }
    }

    // idx0: ansatz1 layer1, frame I (identical to verified baseline gates)
    const float Sr0 = u00r[0][0], Tr0 = u01r[0][0];
    const v2 Sin0 = (v2){-u00i[0][0], u00i[0][0]};
    const v2 Tin0 = (v2){-u01i[0][0], u01i[0][0]};
    float U0r[3], B0r[3]; v2 A0n[3], W0n[3];
    {
        const float zq3[3] = { z1f, z2f, z3f };
#pragma unroll
        for (int q = 1; q < 4; ++q) {
            float z = zq3[q-1];
            U0r[q-1] = u00r[0][q];
            A0n[q-1] = (v2){-z*u00i[0][q], z*u00i[0][q]};
            B0r[q-1] = z*u01r[0][q];
            W0n[q-1] = (v2){-u01i[0][q], u01i[0][q]};
        }
    }
    // idx1: V = H*U (unscaled, det -1: [[a,b],[b~,-a~]]), frame Q1 = R.
    // masks: q0:{n0,n1} q1:{n1,n2} q2:{n2,n3} q3:{n0,n1,n3}
    // sigma: {z123, n0*z1, n0*z12, n0*z123}  (det-1 fold: sigma on diag-REAL & off-IMAG)
    float d1r[4], o1r[4]; v2 d1i[4], o1i[4];
    {
        const float zf1[4] = { z123, z1f, z12, z123 };
#pragma unroll
        for (int q = 0; q < 4; ++q) {
            float ar = u00r[1][q] - u01r[1][q];
            float ai = u00i[1][q] + u01i[1][q];
            float br = u00r[1][q] + u01r[1][q];
            float bi = u01i[1][q] - u00i[1][q];
            float z = zf1[q];
            d1r[q] = z*ar;
            d1i[q] = (v2){-ai, ai};
            o1r[q] = br;
            o1i[q] = (v2){-z*bi, z*bi};
        }
    }
    // idx2: ansatz2 layer1 (det +1), frame Q2. masks: q0:{n0} q1:{n0,n2} q2:{n0,n3} q3:{n1}
    // sigma: {n0*z23, z2, z3, z1}  (det+1 fold: sigma on diag-IMAG & off-REAL)
    float s2r[4], t2r[4]; v2 s2i[4], t2i[4];
    {
        const float zf2[4] = { z23, z2f, z3f, z1f };
#pragma unroll
        for (int q = 0; q < 4; ++q) {
            float z = zf2[q];
            s2r[q] = u00r[2][q];
            s2i[q] = (v2){-z*u00i[2][q], z*u00i[2][q]};
            t2r[q] = z*u01r[2][q];
            t2i[q] = (v2){-u01i[2][q], u01i[2][q]};
        }
    }
    // idx3: ansatz2 layer2, frame Q3. masks: q0:{n2} q1:{n2,n3} q2:{n0,n1,n3} q3:{n1,n2}
    // sigma: {z123, n0*z3, n0, n0*z1}
    float s3r[4], t3r[4]; v2 s3i[4], t3i[4];
    {
        const float zf3[4] = { z123, z3f, 1.0f, z1f };
#pragma unroll
        for (int q = 0; q < 4; ++q) {
            float z = zf3[q];
            s3r[q] = u00r[3][q];
            s3i[q] = (v2){-z*u00i[3][q], z*u00i[3][q]};
            t3r[q] = z*u01r[3][q];
            t3i[q] = (v2){-u01i[3][q], u01i[3][q]};
        }
    }

    // ---- KAN cubic coeffs (lane 'sub' = input dim); REVC folded.
    float kQ0[7], kQ1[7], kQ2[7], kQ3[7], kBW[7];
#pragma unroll
    for (int r = 0; r < 7; ++r) {
        float sw0 = ksw[r*16 + sub*4 + 0], sw1 = ksw[r*16 + sub*4 + 1];
        float sw2 = ksw[r*16 + sub*4 + 2], sw3 = ksw[r*16 + sub*4 + 3];
        const float f = REVC / 48.0f;
        kQ0[r] = f * (sw0 + 23.f*sw1 + 23.f*sw2 + sw3);
        kQ1[r] = f * (-3.f*sw0 - 15.f*sw1 + 15.f*sw2 + 3.f*sw3);
        kQ2[r] = f * (3.f*sw0 - 3.f*sw1 - 3.f*sw2 + 3.f*sw3);
        kQ3[r] = f * (-sw0 + 3.f*sw1 - 3.f*sw2 + sw3);
        kBW[r] = REVC * kbw[r*4 + sub];
    }
    const int pr0[3] = {0, 1, 3}, pr1[3] = {4, 2, 6};
    v2 Q0p[3], Q1p[3], Q2p[3], Q3p[3], BWp[3];
#pragma unroll
    for (int j = 0; j < 3; ++j) {
        Q0p[j] = (v2){kQ0[pr0[j]], kQ0[pr1[j]]};
        Q1p[j] = (v2){kQ1[pr0[j]], kQ1[pr1[j]]};
        Q2p[j] = (v2){kQ2[pr0[j]], kQ2[pr1[j]]};
        Q3p[j] = (v2){kQ3[pr0[j]], kQ3[pr1[j]]};
        BWp[j] = (v2){kBW[pr0[j]], kBW[pr1[j]]};
    }

    // measurement: residual Walsh-strip + /256 folded into one per-lane scale
    // EV0=sum z1z3*dl, EV1=sum z1z2*dl, EV2=sum z1z2*s, EV3=sum z2*dl
    const float SCL = (is0 ? z13 : (is1 ? z12 : (is2 ? z12 : z2f))) * (1.0f/256.0f);

    // ---- per-element state: hidden pairs + inputs
    v2 H04, H12, H36;
    float H5;
    const float4* inp4 = (const float4*)inputs;
    H04 = (v2){REVC*initial_t[e*7+0], REVC*initial_t[e*7+4]};
    H12 = (v2){REVC*initial_t[e*7+1], REVC*initial_t[e*7+2]};
    H36 = (v2){REVC*initial_t[e*7+3], REVC*initial_t[e*7+6]};
    H5  = REVC*initial_t[e*7+5];
    const long BASE = (long)e * S;
    float4 XC = inp4[BASE];

    const float NQPI = -0.7853981633974483f;   // -pi/4
    float XK = 0.f;
    v2 A0, A1;

#pragma unroll 1
    for (int t = 0; t < S; ++t) {
        const int tn = (t + 1 < S) ? t + 1 : S - 1;
        float4 XN = inp4[BASE + tn];

        // ---- fm(hidden) on |0000>: amp = e^{i*2pi*sig}  (frame I)
        {
            float base = H12.x * z1f;
            base = fmaf(H12.y, z2f, base);
            base = fmaf(H36.x, z3f, base);
            base = fmaf(H5,   z12, base);
            base = fmaf(H36.y, z23, base);
            float w = fmaf(H04.y, z1f, H04.x);
            float s0, c0, s1, c1;
            fsincos(base + w, &s0, &c0);
            fsincos(base - w, &s1, &c1);
            A0 = (v2){c0, s0};
            A1 = (v2){c1, s1};
        }

        // ======== L0: ansatz1 layer1 (frame I). Ring R1 delayed. ========
        {   // q0: local pair
            v2 n0 = gup(A0, A1, Sr0,  Sin0,  Tr0, Tin0);
            v2 n1 = gup(A1, A0, Sr0, -Sin0, -Tr0, Tin0);
            A0 = n0; A1 = n1;
        }
        // q1: ror8, sigma z1
        A0 = gup(A0, ror8v(A0), U0r[0], A0n[0], B0r[0], W0n[0]);
        A1 = gup(A1, ror8v(A1), U0r[0], A0n[0], B0r[0], W0n[0]);
        // q2: lx1, sigma z2
        A0 = gup(A0, lx1v(A0), U0r[1], A0n[1], B0r[1], W0n[1]);
        A1 = gup(A1, lx1v(A1), U0r[1], A0n[1], B0r[1], W0n[1]);
        // q3: lx2, sigma z3
        A0 = gup(A0, lx2v(A0), U0r[2], A0n[2], B0r[2], W0n[2]);
        A1 = gup(A1, lx2v(A1), U0r[2], A0n[2], B0r[2], W0n[2]);

        // ======== L1': H-folded ansatz1 layer2 (det -1), frame Q1 ========
        {   // g0: mask {n0,n1}: partner=ror8(other); sigma z123 (same both)
            v2 p0 = ror8v(A1), p1 = ror8v(A0);
            v2 n0 = gup(A0, p0, d1r[0], d1i[0], o1r[0], o1i[0]);
            v2 n1 = gup(A1, p1, d1r[0], d1i[0], o1r[0], o1i[0]);
            A0 = n0; A1 = n1;
        }
        // g1: mask {n1,n2}: same-reg chain; sigma n0*z1 -> A1 negs (dr,oi)
        A0 = gup(A0, r8lx1v(A0),  d1r[1], d1i[1], o1r[1],  o1i[1]);
        A1 = gup(A1, r8lx1v(A1), -d1r[1], d1i[1], o1r[1], -o1i[1]);
        // g2: mask {n2,n3}: quad xor3; sigma n0*z12
        A0 = gup(A0, x3v(A0),  d1r[2], d1i[2], o1r[2],  o1i[2]);
        A1 = gup(A1, x3v(A1), -d1r[2], d1i[2], o1r[2], -o1i[2]);
        {   // g3: mask {n0,n1,n3}: partner=ror8(lx2(other)); sigma n0*z123
            v2 p0 = r8lx2v(A1), p1 = r8lx2v(A0);
            v2 n0 = gup(A0, p0,  d1r[3], d1i[3], o1r[3],  o1i[3]);
            v2 n1 = gup(A1, p1, -d1r[3], d1i[3], o1r[3], -o1i[3]);
            A0 = n0; A1 = n1;
        }

        // ======== Phase_x (diag), frame Q2: Z0->n0*z23, Z1->z2, Z2->z3, Z3->z1,
        //          Z0Z1->n0*z3, Z1Z2->z23, Z2Z3->z13 ========
        {
            float hx0 = REVC*XC.x, hx1 = REVC*XC.y;
            float hx2 = REVC*XC.z, hx3 = REVC*XC.w;
            float u0 = fmaf(4.f, hx0, 1.f);
            float u1 = fmaf(4.f, hx1, 1.f);
            float u2 = fmaf(4.f, hx2, 1.f);
            float u3 = fmaf(4.f, hx3, 1.f);
            float he4 = NQPI * (u0*u1);
            float he5 = NQPI * (u1*u2);
            float he6 = NQPI * (u2*u3);

            float base = hx1 * z2f;
            base = fmaf(hx2, z3f, base);
            base = fmaf(hx3, z1f, base);
            base = fmaf(he5, z23, base);
            base = fmaf(he6, z13, base);
            float w = fmaf(he4, z3f, hx0 * z23);
            float s0, c0, s1, c1;
            fsincos(base + w, &s0, &c0);
            fsincos(base - w, &s1, &c1);
            v2 sn0 = (v2){-s0, s0};
            v2 sn1 = (v2){-s1, s1};
            A0 = vfma(vswap(A0), sn0, A0 * c0);
            A1 = vfma(vswap(A1), sn1, A1 * c1);
        }

        // ======== L2: ansatz2 layer1 (det +1), frame Q2 ========
        {   // g0: mask {n0} local; sigma n0*z23 -> A1 negs (di,orr)
            v2 n0 = gup(A0, A1, s2r[0],  s2i[0],  t2r[0], t2i[0]);
            v2 n1 = gup(A1, A0, s2r[0], -s2i[0], -t2r[0], t2i[0]);
            A0 = n0; A1 = n1;
        }
        {   // g1: mask {n0,n2}: partner=lx1(other); sigma z2 (same)
            v2 p0 = lx1v(A1), p1 = lx1v(A0);
            v2 n0 = gup(A0, p0, s2r[1], s2i[1], t2r[1], t2i[1]);
            v2 n1 = gup(A1, p1, s2r[1], s2i[1], t2r[1], t2i[1]);
            A0 = n0; A1 = n1;
        }
        {   // g2: mask {n0,n3}: partner=lx2(other); sigma z3 (same)
            v2 p0 = lx2v(A1), p1 = lx2v(A0);
            v2 n0 = gup(A0, p0, s2r[2], s2i[2], t2r[2], t2i[2]);
            v2 n1 = gup(A1, p1, s2r[2], s2i[2], t2r[2], t2i[2]);
            A0 = n0; A1 = n1;
        }
        // g3: mask {n1}: ror8 same; sigma z1 (same)
        A0 = gup(A0, ror8v(A0), s2r[3], s2i[3], t2r[3], t2i[3]);
        A1 = gup(A1, ror8v(A1), s2r[3], s2i[3], t2r[3], t2i[3]);

        // ======== L3: ansatz2 layer2 (det +1), frame Q3 ========
        // g0: mask {n2}: lx1 same; sigma z123 (same)
        A0 = gup(A0, lx1v(A0), s3r[0], s3i[0], t3r[0], t3i[0]);
        A1 = gup(A1, lx1v(A1), s3r[0], s3i[0], t3r[0], t3i[0]);
        // g1: mask {n2,n3}: quad xor3; sigma n0*z3 -> A1 negs
        A0 = gup(A0, x3v(A0),  s3r[1],  s3i[1],  t3r[1], t3i[1]);
        A1 = gup(A1, x3v(A1),  s3r[1], -s3i[1], -t3r[1], t3i[1]);
        {   // g2: mask {n0,n1,n3}: partner=ror8(lx2(other)); sigma n0
            v2 p0 = r8lx2v(A1), p1 = r8lx2v(A0);
            v2 n0 = gup(A0, p0, s3r[2],  s3i[2],  t3r[2], t3i[2]);
            v2 n1 = gup(A1, p1, s3r[2], -s3i[2], -t3r[2], t3i[2]);
            A0 = n0; A1 = n1;
        }
        // g3: mask {n1,n2}: ror8(lx1(same)); sigma n0*z1 -> A1 negs
        A0 = gup(A0, r8lx1v(A0), s3r[3],  s3i[3],  t3r[3], t3i[3]);
        A1 = gup(A1, r8lx1v(A1), s3r[3], -s3i[3], -t3r[3], t3i[3]);

        // ---- measurement, frame Q4 folded into Walsh butterflies (probs x256)
        {
            v2 m0 = A0 * A0, m1 = A1 * A1;
            float pa = m0.x + m0.y;
            float pb = m1.x + m1.y;
            float s  = pa + pb;
            float dl = pa - pb;
            float rd = ror8(dl);
            float tA = dl - rd;                    // antisym b3
            float vA = dl + rd;                    // sym b3
            float t1 = tA - lx1(tA); t1 += lx2(t1);  // z1z2*EV1
            float t0 = tA + lx1(tA); t0 -= lx2(t0);  // z1z3*EV0
            float v1 = vA - lx1(vA); v1 += lx2(v1);  // z2*EV3
            float wA = s - ror8(s);
            float w1m = wA - lx1(wA); w1m += lx2(w1m);  // z1z2*EV2
            float pre = is0 ? t0 : (is1 ? t1 : (is2 ? w1m : v1));
            XK = pre * SCL;
        }

        // ---- KAN (packed pairs): lane sub = input dim; quad-reduce sums dims
        {
            float xk = XK;
            float eneg = __builtin_amdgcn_exp2f(xk * -1.44269504088896f);
            float silu = xk * __builtin_amdgcn_rcpf(1.0f + eneg);
            v2 xs = vsplat(xk), ss = vsplat(silu);
            v2 op[3];
#pragma unroll
            for (int k = 0; k < 3; ++k) {
                v2 o = vfma(Q3p[k], xs, Q2p[k]);
                o = vfma(o, xs, Q1p[k]);
                o = vfma(o, xs, Q0p[k]);
                o = vfma(BWp[k], ss, o);
                o = o + (v2){lx1(o.x), lx1(o.y)};
                o = o + (v2){lx2(o.x), lx2(o.y)};
                op[k] = o;
            }
            {   // scalar r=5
                float o = fmaf(kQ3[5], xk, kQ2[5]);
                o = fmaf(o, xk, kQ1[5]);
                o = fmaf(o, xk, kQ0[5]);
                o = fmaf(kBW[5], silu, o);
                o += lx1(o); o += lx2(o);
                H5 = o;
            }
            H04 = op[0]; H12 = op[1]; H36 = op[2];
            XC = XN;
        }
    }

    // ---- classifier head: quad lanes hold ev0..ev3 per element
    {
        float xk  = XK;
        float ev1 = qperm<0x55>(xk);
        float ev2 = qperm<0xAA>(xk);
        float ev3 = qperm<0xFF>(xk);
        if (sub == 0 && !b1) {
            float acc = cb2[0];
#pragma unroll
            for (int i = 0; i < 16; ++i) {
                float h = cb1[i] + w1[i*4+0]*xk + w1[i*4+1]*ev1
                        + w1[i*4+2]*ev2 + w1[i*4+3]*ev3;
                h = fmaxf(h, 0.0f);
                acc += w2[i]*h;
            }
            out[e] = acc;
        }
    }
}

extern "C" void kernel_launch(void* const* d_in, const int* in_sizes, int n_in,
                              void* d_out, int out_size, void* d_ws, size_t ws_size,
                              hipStream_t stream) {
    const float* inputs    = (const float*)d_in[0];
    const float* initial_t = (const float*)d_in[1];
    const float* p1        = (const float*)d_in[2];
    const float* p2        = (const float*)d_in[3];
    const float* kbw       = (const float*)d_in[4];
    const float* ksw       = (const float*)d_in[5];
    const float* w1        = (const float*)d_in[6];
    const float* cb1       = (const float*)d_in[7];
    const float* w2        = (const float*)d_in[8];
    const float* cb2       = (const float*)d_in[9];

    const int B = in_sizes[1] / 7;            // 16384
    const int S = in_sizes[0] / (B * 4);      // 256

    const int threads = B * 8;                // 8 lanes/slot, 1 element/thread
    const int block = 256;
    const int grid = (threads + block - 1) / block;   // 512 blocks -> 2 waves/SIMD

    qrnn_kernel<<<grid, block, 0, stream>>>(inputs, initial_t, p1, p2, kbw, ksw,
                                            w1, cb1, w2, cb2, (float*)d_out, B, S);
}

// Round 4
// 300.211 us; speedup vs baseline: 1.2024x; 1.0582x over previous
//
#include <hip/hip_runtime.h>
#include <math.h>

#define DEV static __device__ __forceinline__

typedef float v2 __attribute__((ext_vector_type(2)));

// DPP helpers — used where forwarding latency matters (measurement/KAN chains).
template<int CTRL>
DEV float qperm(float x) {
    return __int_as_float(__builtin_amdgcn_mov_dpp(__float_as_int(x), CTRL, 0xF, 0xF, true));
}
DEV float lx1(float v)  { return qperm<0xB1>(v); }   // xor lane bit0 (stored q2)
DEV float lx2(float v)  { return qperm<0x4E>(v); }   // xor lane bit1 (stored q3)
DEV float ror8(float v) { return qperm<0x128>(v); }  // xor lane bit3 (stored q1)
DEV float rfl(float x)  { return __int_as_float(__builtin_amdgcn_readfirstlane(__float_as_int(x))); }

// ds_swizzle XOR-mask lane permutes — LDS pipe (no LDS memory, no bank
// conflicts). Frees VALU issue slots; with 2 waves/SIMD the other wave's
// VALU work co-issues with these. BitMode offset = (xor<<10)|0x1F.
template<int MASK>
DEV float dswz(float x) {
    return __int_as_float(__builtin_amdgcn_ds_swizzle(__float_as_int(x), (MASK << 10) | 0x1F));
}
template<int MASK>
DEV v2 dswzv(v2 a) { return (v2){dswz<MASK>(a.x), dswz<MASK>(a.y)}; }
// masks: n1=8 (lane bit3), n2=1 (bit0), n3=2 (bit1), n1n2=9, n1n3=10, n2n3=3

DEV v2 vswap(v2 a)  { return __builtin_shufflevector(a, a, 1, 0); }
DEV v2 vsplat(float f) { return (v2){f, f}; }
DEV v2 vfma(v2 a, v2 b, v2 c) { return __builtin_elementwise_fma(a, b, c); }

// generalized masked-rot pair update: n = A*dr + swap(A)*di + P*orr + swap(P)*oi
// (sigma sign functionals are pre-folded into dr/di/orr/oi per lane; A1-side
//  sign flips are passed as negated operands -> free VOP3 source modifiers)
DEV v2 gup(v2 A, v2 P, float dr, v2 di, float orr, v2 oi) {
    v2 n = A * dr;
    n = vfma(vswap(A), di, n);
    n = vfma(P, vsplat(orr), n);
    n = vfma(vswap(P), oi, n);
    return n;
}

// Cheap sincos in REVOLUTIONS: v_fract + v_sin + v_cos.
DEV void fsincos(float rev, float* s, float* c) {
    float f = __builtin_amdgcn_fractf(rev);
    *s = __builtin_amdgcn_sinf(f);
    *c = __builtin_amdgcn_cosf(f);
}

__global__ __launch_bounds__(256, 2)
void qrnn_kernel(const float* __restrict__ inputs, const float* __restrict__ initial_t,
                 const float* __restrict__ p1, const float* __restrict__ p2,
                 const float* __restrict__ kbw, const float* __restrict__ ksw,
                 const float* __restrict__ w1, const float* __restrict__ cb1,
                 const float* __restrict__ w2, const float* __restrict__ cb2,
                 float* __restrict__ out, int B, int S)
{
    // 8 lanes/slot, ONE element per thread -> B*8 threads = 512 blocks
    // = 2 waves/SIMD. Gate partner fetches go through ds_swizzle (LDS pipe)
    // so the two waves co-issue VALU + swizzle; DPP retained for the short
    // butterfly chains in measurement/KAN.
    // lane bit0->stored q2, bit1->stored q3, bit3->stored q1; bit2 = slot select.
    // CNOT rings are never applied: they are delayed as a pending linear frame Q
    // and folded into later gates' partner masks + Walsh sign constants.
    const int tid    = blockIdx.x * blockDim.x + threadIdx.x;
    const int lane16 = threadIdx.x & 15;
    const int e      = (tid >> 4) * 2 + ((lane16 >> 2) & 1);
    if (e >= B) return;
    const int sub    = lane16 & 3;
    const bool b1    = ((lane16 >> 3) & 1) != 0;
    const bool b2 = (sub & 1) != 0, b3 = (sub & 2) != 0;
    const float z2f = b2 ? -1.f : 1.f;
    const float z3f = b3 ? -1.f : 1.f;
    const float z1f = b1 ? -1.f : 1.f;
    const float z12 = z1f * z2f, z23 = z2f * z3f, z13 = z1f * z3f;
    const float z123 = z1f * z23;
    const bool is0 = (sub == 0), is1 = (sub == 1), is2 = (sub == 2);

    // Angles in REVOLUTIONS with -0.5 half-angle folded: stored = -rad/(4*pi).
    const float REVC = -0.07957747154594767f;   // -1/(4*pi)

    // ---- one-time: 16 base Rot matrices (input-constant)
    float u00r[4][4], u00i[4][4], u01r[4][4], u01i[4][4];
    const float* PP[2] = { p1, p2 };
#pragma unroll
    for (int aI = 0; aI < 2; ++aI) {
        const float* pp = PP[aI];
#pragma unroll
        for (int l = 0; l < 2; ++l) {
            const int idx = aI*2 + l;
#pragma unroll
            for (int q = 0; q < 4; ++q) {
                float phi = pp[l*12 + q*3 + 0];
                float tht = pp[l*12 + q*3 + 1];
                float omg = pp[l*12 + q*3 + 2];
                float st, ct; sincosf(0.5f*tht, &st, &ct);
                float sA, cA, sB, cB;
                sincosf(0.5f*(phi + omg), &sA, &cA);
                sincosf(0.5f*(phi - omg), &sB, &cB);
                u00r[idx][q] = rfl( cA*ct); u00i[idx][q] = rfl(-sA*ct);
                u01r[idx][q] = rfl(-cB*st); u01i[idx][q] = rfl(-sB*st);
            }
        }
    }

    // idx0: ansatz1 layer1, frame I (identical to verified baseline gates)
    const float Sr0 = u00r[0][0], Tr0 = u01r[0][0];
    const v2 Sin0 = (v2){-u00i[0][0], u00i[0][0]};
    const v2 Tin0 = (v2){-u01i[0][0], u01i[0][0]};
    float U0r[3], B0r[3]; v2 A0n[3], W0n[3];
    {
        const float zq3[3] = { z1f, z2f, z3f };
#pragma unroll
        for (int q = 1; q < 4; ++q) {
            float z = zq3[q-1];
            U0r[q-1] = u00r[0][q];
            A0n[q-1] = (v2){-z*u00i[0][q], z*u00i[0][q]};
            B0r[q-1] = z*u01r[0][q];
            W0n[q-1] = (v2){-u01i[0][q], u01i[0][q]};
        }
    }
    // idx1: V = H*U (unscaled, det -1: [[a,b],[b~,-a~]]), frame Q1 = R.
    // masks: q0:{n0,n1} q1:{n1,n2} q2:{n2,n3} q3:{n0,n1,n3}
    // sigma: {z123, n0*z1, n0*z12, n0*z123}  (det-1 fold: sigma on diag-REAL & off-IMAG)
    float d1r[4], o1r[4]; v2 d1i[4], o1i[4];
    {
        const float zf1[4] = { z123, z1f, z12, z123 };
#pragma unroll
        for (int q = 0; q < 4; ++q) {
            float ar = u00r[1][q] - u01r[1][q];
            float ai = u00i[1][q] + u01i[1][q];
            float br = u00r[1][q] + u01r[1][q];
            float bi = u01i[1][q] - u00i[1][q];
            float z = zf1[q];
            d1r[q] = z*ar;
            d1i[q] = (v2){-ai, ai};
            o1r[q] = br;
            o1i[q] = (v2){-z*bi, z*bi};
        }
    }
    // idx2: ansatz2 layer1 (det +1), frame Q2. masks: q0:{n0} q1:{n0,n2} q2:{n0,n3} q3:{n1}
    // sigma: {n0*z23, z2, z3, z1}  (det+1 fold: sigma on diag-IMAG & off-REAL)
    float s2r[4], t2r[4]; v2 s2i[4], t2i[4];
    {
        const float zf2[4] = { z23, z2f, z3f, z1f };
#pragma unroll
        for (int q = 0; q < 4; ++q) {
            float z = zf2[q];
            s2r[q] = u00r[2][q];
            s2i[q] = (v2){-z*u00i[2][q], z*u00i[2][q]};
            t2r[q] = z*u01r[2][q];
            t2i[q] = (v2){-u01i[2][q], u01i[2][q]};
        }
    }
    // idx3: ansatz2 layer2, frame Q3. masks: q0:{n2} q1:{n2,n3} q2:{n0,n1,n3} q3:{n1,n2}
    // sigma: {z123, n0*z3, n0, n0*z1}
    float s3r[4], t3r[4]; v2 s3i[4], t3i[4];
    {
        const float zf3[4] = { z123, z3f, 1.0f, z1f };
#pragma unroll
        for (int q = 0; q < 4; ++q) {
            float z = zf3[q];
            s3r[q] = u00r[3][q];
            s3i[q] = (v2){-z*u00i[3][q], z*u00i[3][q]};
            t3r[q] = z*u01r[3][q];
            t3i[q] = (v2){-u01i[3][q], u01i[3][q]};
        }
    }

    // ---- KAN cubic coeffs (lane 'sub' = input dim); REVC folded.
    float kQ0[7], kQ1[7], kQ2[7], kQ3[7], kBW[7];
#pragma unroll
    for (int r = 0; r < 7; ++r) {
        float sw0 = ksw[r*16 + sub*4 + 0], sw1 = ksw[r*16 + sub*4 + 1];
        float sw2 = ksw[r*16 + sub*4 + 2], sw3 = ksw[r*16 + sub*4 + 3];
        const float f = REVC / 48.0f;
        kQ0[r] = f * (sw0 + 23.f*sw1 + 23.f*sw2 + sw3);
        kQ1[r] = f * (-3.f*sw0 - 15.f*sw1 + 15.f*sw2 + 3.f*sw3);
        kQ2[r] = f * (3.f*sw0 - 3.f*sw1 - 3.f*sw2 + 3.f*sw3);
        kQ3[r] = f * (-sw0 + 3.f*sw1 - 3.f*sw2 + sw3);
        kBW[r] = REVC * kbw[r*4 + sub];
    }
    const int pr0[3] = {0, 1, 3}, pr1[3] = {4, 2, 6};
    v2 Q0p[3], Q1p[3], Q2p[3], Q3p[3], BWp[3];
#pragma unroll
    for (int j = 0; j < 3; ++j) {
        Q0p[j] = (v2){kQ0[pr0[j]], kQ0[pr1[j]]};
        Q1p[j] = (v2){kQ1[pr0[j]], kQ1[pr1[j]]};
        Q2p[j] = (v2){kQ2[pr0[j]], kQ2[pr1[j]]};
        Q3p[j] = (v2){kQ3[pr0[j]], kQ3[pr1[j]]};
        BWp[j] = (v2){kBW[pr0[j]], kBW[pr1[j]]};
    }

    // measurement: residual Walsh-strip + /256 folded into one per-lane scale
    // EV0=sum z1z3*dl, EV1=sum z1z2*dl, EV2=sum z1z2*s, EV3=sum z2*dl
    const float SCL = (is0 ? z13 : (is1 ? z12 : (is2 ? z12 : z2f))) * (1.0f/256.0f);

    // ---- per-element state: hidden pairs + inputs
    v2 H04, H12, H36;
    float H5;
    const float4* inp4 = (const float4*)inputs;
    H04 = (v2){REVC*initial_t[e*7+0], REVC*initial_t[e*7+4]};
    H12 = (v2){REVC*initial_t[e*7+1], REVC*initial_t[e*7+2]};
    H36 = (v2){REVC*initial_t[e*7+3], REVC*initial_t[e*7+6]};
    H5  = REVC*initial_t[e*7+5];
    const long BASE = (long)e * S;
    float4 XC = inp4[BASE];

    const float NQPI = -0.7853981633974483f;   // -pi/4
    float XK = 0.f;
    v2 A0, A1;

#pragma unroll 1
    for (int t = 0; t < S; ++t) {
        const int tn = (t + 1 < S) ? t + 1 : S - 1;
        float4 XN = inp4[BASE + tn];

        // ---- fm(hidden) on |0000>: amp = e^{i*2pi*sig}  (frame I)
        {
            float base = H12.x * z1f;
            base = fmaf(H12.y, z2f, base);
            base = fmaf(H36.x, z3f, base);
            base = fmaf(H5,   z12, base);
            base = fmaf(H36.y, z23, base);
            float w = fmaf(H04.y, z1f, H04.x);
            float s0, c0, s1, c1;
            fsincos(base + w, &s0, &c0);
            fsincos(base - w, &s1, &c1);
            A0 = (v2){c0, s0};
            A1 = (v2){c1, s1};
        }

        // ======== L0: ansatz1 layer1 (frame I). Ring R1 delayed. ========
        {   // q0: local pair
            v2 n0 = gup(A0, A1, Sr0,  Sin0,  Tr0, Tin0);
            v2 n1 = gup(A1, A0, Sr0, -Sin0, -Tr0, Tin0);
            A0 = n0; A1 = n1;
        }
        // q1: xor n1, sigma z1
        A0 = gup(A0, dswzv<8>(A0), U0r[0], A0n[0], B0r[0], W0n[0]);
        A1 = gup(A1, dswzv<8>(A1), U0r[0], A0n[0], B0r[0], W0n[0]);
        // q2: xor n2, sigma z2
        A0 = gup(A0, dswzv<1>(A0), U0r[1], A0n[1], B0r[1], W0n[1]);
        A1 = gup(A1, dswzv<1>(A1), U0r[1], A0n[1], B0r[1], W0n[1]);
        // q3: xor n3, sigma z3
        A0 = gup(A0, dswzv<2>(A0), U0r[2], A0n[2], B0r[2], W0n[2]);
        A1 = gup(A1, dswzv<2>(A1), U0r[2], A0n[2], B0r[2], W0n[2]);

        // ======== L1': H-folded ansatz1 layer2 (det -1), frame Q1 ========
        {   // g0: mask {n0,n1}: partner=xor8(other); sigma z123 (same both)
            v2 p0 = dswzv<8>(A1), p1 = dswzv<8>(A0);
            v2 n0 = gup(A0, p0, d1r[0], d1i[0], o1r[0], o1i[0]);
            v2 n1 = gup(A1, p1, d1r[0], d1i[0], o1r[0], o1i[0]);
            A0 = n0; A1 = n1;
        }
        // g1: mask {n1,n2}: xor9 same-reg; sigma n0*z1 -> A1 negs (dr,oi)
        A0 = gup(A0, dswzv<9>(A0),  d1r[1], d1i[1], o1r[1],  o1i[1]);
        A1 = gup(A1, dswzv<9>(A1), -d1r[1], d1i[1], o1r[1], -o1i[1]);
        // g2: mask {n2,n3}: xor3; sigma n0*z12
        A0 = gup(A0, dswzv<3>(A0),  d1r[2], d1i[2], o1r[2],  o1i[2]);
        A1 = gup(A1, dswzv<3>(A1), -d1r[2], d1i[2], o1r[2], -o1i[2]);
        {   // g3: mask {n0,n1,n3}: partner=xor10(other); sigma n0*z123
            v2 p0 = dswzv<10>(A1), p1 = dswzv<10>(A0);
            v2 n0 = gup(A0, p0,  d1r[3], d1i[3], o1r[3],  o1i[3]);
            v2 n1 = gup(A1, p1, -d1r[3], d1i[3], o1r[3], -o1i[3]);
            A0 = n0; A1 = n1;
        }

        // ======== Phase_x (diag), frame Q2: Z0->n0*z23, Z1->z2, Z2->z3, Z3->z1,
        //          Z0Z1->n0*z3, Z1Z2->z23, Z2Z3->z13 ========
        {
            float hx0 = REVC*XC.x, hx1 = REVC*XC.y;
            float hx2 = REVC*XC.z, hx3 = REVC*XC.w;
            float u0 = fmaf(4.f, hx0, 1.f);
            float u1 = fmaf(4.f, hx1, 1.f);
            float u2 = fmaf(4.f, hx2, 1.f);
            float u3 = fmaf(4.f, hx3, 1.f);
            float he4 = NQPI * (u0*u1);
            float he5 = NQPI * (u1*u2);
            float he6 = NQPI * (u2*u3);

            float base = hx1 * z2f;
            base = fmaf(hx2, z3f, base);
            base = fmaf(hx3, z1f, base);
            base = fmaf(he5, z23, base);
            base = fmaf(he6, z13, base);
            float w = fmaf(he4, z3f, hx0 * z23);
            float s0, c0, s1, c1;
            fsincos(base + w, &s0, &c0);
            fsincos(base - w, &s1, &c1);
            v2 sn0 = (v2){-s0, s0};
            v2 sn1 = (v2){-s1, s1};
            A0 = vfma(vswap(A0), sn0, A0 * c0);
            A1 = vfma(vswap(A1), sn1, A1 * c1);
        }

        // ======== L2: ansatz2 layer1 (det +1), frame Q2 ========
        {   // g0: mask {n0} local; sigma n0*z23 -> A1 negs (di,orr)
            v2 n0 = gup(A0, A1, s2r[0],  s2i[0],  t2r[0], t2i[0]);
            v2 n1 = gup(A1, A0, s2r[0], -s2i[0], -t2r[0], t2i[0]);
            A0 = n0; A1 = n1;
        }
        {   // g1: mask {n0,n2}: partner=xor1(other); sigma z2 (same)
            v2 p0 = dswzv<1>(A1), p1 = dswzv<1>(A0);
            v2 n0 = gup(A0, p0, s2r[1], s2i[1], t2r[1], t2i[1]);
            v2 n1 = gup(A1, p1, s2r[1], s2i[1], t2r[1], t2i[1]);
            A0 = n0; A1 = n1;
        }
        {   // g2: mask {n0,n3}: partner=xor2(other); sigma z3 (same)
            v2 p0 = dswzv<2>(A1), p1 = dswzv<2>(A0);
            v2 n0 = gup(A0, p0, s2r[2], s2i[2], t2r[2], t2i[2]);
            v2 n1 = gup(A1, p1, s2r[2], s2i[2], t2r[2], t2i[2]);
            A0 = n0; A1 = n1;
        }
        // g3: mask {n1}: xor8 same; sigma z1 (same)
        A0 = gup(A0, dswzv<8>(A0), s2r[3], s2i[3], t2r[3], t2i[3]);
        A1 = gup(A1, dswzv<8>(A1), s2r[3], s2i[3], t2r[3], t2i[3]);

        // ======== L3: ansatz2 layer2 (det +1), frame Q3 ========
        // g0: mask {n2}: xor1 same; sigma z123 (same)
        A0 = gup(A0, dswzv<1>(A0), s3r[0], s3i[0], t3r[0], t3i[0]);
        A1 = gup(A1, dswzv<1>(A1), s3r[0], s3i[0], t3r[0], t3i[0]);
        // g1: mask {n2,n3}: xor3; sigma n0*z3 -> A1 negs
        A0 = gup(A0, dswzv<3>(A0),  s3r[1],  s3i[1],  t3r[1], t3i[1]);
        A1 = gup(A1, dswzv<3>(A1),  s3r[1], -s3i[1], -t3r[1], t3i[1]);
        {   // g2: mask {n0,n1,n3}: partner=xor10(other); sigma n0
            v2 p0 = dswzv<10>(A1), p1 = dswzv<10>(A0);
            v2 n0 = gup(A0, p0, s3r[2],  s3i[2],  t3r[2], t3i[2]);
            v2 n1 = gup(A1, p1, s3r[2], -s3i[2], -t3r[2], t3i[2]);
            A0 = n0; A1 = n1;
        }
        // g3: mask {n1,n2}: xor9 same; sigma n0*z1 -> A1 negs
        A0 = gup(A0, dswzv<9>(A0), s3r[3],  s3i[3],  t3r[3], t3i[3]);
        A1 = gup(A1, dswzv<9>(A1), s3r[3], -s3i[3], -t3r[3], t3i[3]);

        // ---- measurement, frame Q4 folded into Walsh butterflies (probs x256)
        {
            v2 m0 = A0 * A0, m1 = A1 * A1;
            float pa = m0.x + m0.y;
            float pb = m1.x + m1.y;
            float s  = pa + pb;
            float dl = pa - pb;
            float rd = ror8(dl);
            float tA = dl - rd;                    // antisym b3
            float vA = dl + rd;                    // sym b3
            float t1 = tA - lx1(tA); t1 += lx2(t1);  // z1z2*EV1
            float t0 = tA + lx1(tA); t0 -= lx2(t0);  // z1z3*EV0
            float v1 = vA - lx1(vA); v1 += lx2(v1);  // z2*EV3
            float wA = s - ror8(s);
            float w1m = wA - lx1(wA); w1m += lx2(w1m);  // z1z2*EV2
            float pre = is0 ? t0 : (is1 ? t1 : (is2 ? w1m : v1));
            XK = pre * SCL;
        }

        // ---- KAN (packed pairs): lane sub = input dim; quad-reduce sums dims
        {
            float xk = XK;
            float eneg = __builtin_amdgcn_exp2f(xk * -1.44269504088896f);
            float silu = xk * __builtin_amdgcn_rcpf(1.0f + eneg);
            v2 xs = vsplat(xk), ss = vsplat(silu);
            v2 op[3];
#pragma unroll
            for (int k = 0; k < 3; ++k) {
                v2 o = vfma(Q3p[k], xs, Q2p[k]);
                o = vfma(o, xs, Q1p[k]);
                o = vfma(o, xs, Q0p[k]);
                o = vfma(BWp[k], ss, o);
                o = o + (v2){lx1(o.x), lx1(o.y)};
                o = o + (v2){lx2(o.x), lx2(o.y)};
                op[k] = o;
            }
            {   // scalar r=5
                float o = fmaf(kQ3[5], xk, kQ2[5]);
                o = fmaf(o, xk, kQ1[5]);
                o = fmaf(o, xk, kQ0[5]);
                o = fmaf(kBW[5], silu, o);
                o += lx1(o); o += lx2(o);
                H5 = o;
            }
            H04 = op[0]; H12 = op[1]; H36 = op[2];
            XC = XN;
        }
    }

    // ---- classifier head: quad lanes hold ev0..ev3 per element
    {
        float xk  = XK;
        float ev1 = qperm<0x55>(xk);
        float ev2 = qperm<0xAA>(xk);
        float ev3 = qperm<0xFF>(xk);
        if (sub == 0 && !b1) {
            float acc = cb2[0];
#pragma unroll
            for (int i = 0; i < 16; ++i) {
                float h = cb1[i] + w1[i*4+0]*xk + w1[i*4+1]*ev1
                        + w1[i*4+2]*ev2 + w1[i*4+3]*ev3;
                h = fmaxf(h, 0.0f);
                acc += w2[i]*h;
            }
            out[e] = acc;
        }
    }
}

extern "C" void kernel_launch(void* const* d_in, const int* in_sizes, int n_in,
                              void* d_out, int out_size, void* d_ws, size_t ws_size,
                              hipStream_t stream) {
    const float* inputs    = (const float*)d_in[0];
    const float* initial_t = (const float*)d_in[1];
    const float* p1        = (const float*)d_in[2];
    const float* p2        = (const float*)d_in[3];
    const float* kbw       = (const float*)d_in[4];
    const float* ksw       = (const float*)d_in[5];
    const float* w1        = (const float*)d_in[6];
    const float* cb1       = (const float*)d_in[7];
    const float* w2        = (const float*)d_in[8];
    const float* cb2       = (const float*)d_in[9];

    const int B = in_sizes[1] / 7;            // 16384
    const int S = in_sizes[0] / (B * 4);      // 256

    const int threads = B * 8;                // 8 lanes/slot, 1 element/thread
    const int block = 256;
    const int grid = (threads + block - 1) / block;   // 512 blocks -> 2 waves/SIMD

    qrnn_kernel<<<grid, block, 0, stream>>>(inputs, initial_t, p1, p2, kbw, ksw,
                                            w1, cb1, w2, cb2, (float*)d_out, B, S);
}

// Round 5
// 298.993 us; speedup vs baseline: 1.2073x; 1.0041x over previous
//
#include <hip/hip_runtime.h>
#include <math.h>

#define DEV static __device__ __forceinline__

typedef float v2 __attribute__((ext_vector_type(2)));

// DPP helpers — VALU pipe, ~1-2 cyc forwarding. Used for the A0-side partner
// fetch of every gate (covers the A1-side ds_swizzle latency) and for the
// short butterfly chains in measurement/KAN.
template<int CTRL>
DEV float qperm(float x) {
    return __int_as_float(__builtin_amdgcn_mov_dpp(__float_as_int(x), CTRL, 0xF, 0xF, true));
}
DEV float lx1(float v)  { return qperm<0xB1>(v); }   // xor lane bit0 (stored q2)
DEV float lx2(float v)  { return qperm<0x4E>(v); }   // xor lane bit1 (stored q3)
DEV float x3f_(float v) { return qperm<0x1B>(v); }   // xor lane bits 0&1
DEV float ror8(float v) { return qperm<0x128>(v); }  // xor lane bit3 (stored q1)
DEV float rfl(float x)  { return __int_as_float(__builtin_amdgcn_readfirstlane(__float_as_int(x))); }

DEV v2 ror8v(v2 a){ return (v2){ror8(a.x), ror8(a.y)}; }
DEV v2 lx1v(v2 a) { return (v2){lx1(a.x), lx1(a.y)}; }
DEV v2 lx2v(v2 a) { return (v2){lx2(a.x), lx2(a.y)}; }
DEV v2 x3v(v2 a)  { return (v2){x3f_(a.x), x3f_(a.y)}; }
DEV v2 r8lx1v(v2 a){ return (v2){ror8(lx1(a.x)), ror8(lx1(a.y))}; }
DEV v2 r8lx2v(v2 a){ return (v2){ror8(lx2(a.x)), ror8(lx2(a.y))}; }

// ds_swizzle XOR-mask lane permutes — LDS pipe. Issued FIRST in each gate so
// their ~120 cyc latency hides under the DPP-fed gup(A0) that follows.
template<int MASK>
DEV float dswz(float x) {
    return __int_as_float(__builtin_amdgcn_ds_swizzle(__float_as_int(x), (MASK << 10) | 0x1F));
}
template<int MASK>
DEV v2 dswzv(v2 a) { return (v2){dswz<MASK>(a.x), dswz<MASK>(a.y)}; }
// masks: n1=8 (lane bit3), n2=1 (bit0), n3=2 (bit1), n1n2=9, n1n3=10, n2n3=3

DEV v2 vswap(v2 a)  { return __builtin_shufflevector(a, a, 1, 0); }
DEV v2 vsplat(float f) { return (v2){f, f}; }
DEV v2 vfma(v2 a, v2 b, v2 c) { return __builtin_elementwise_fma(a, b, c); }

// generalized masked-rot pair update: n = A*dr + swap(A)*di + P*orr + swap(P)*oi
// (sigma sign functionals are pre-folded into dr/di/orr/oi per lane; A1-side
//  sign flips are passed as negated operands -> free VOP3 source modifiers)
DEV v2 gup(v2 A, v2 P, float dr, v2 di, float orr, v2 oi) {
    v2 n = A * dr;
    n = vfma(vswap(A), di, n);
    n = vfma(P, vsplat(orr), n);
    n = vfma(vswap(P), oi, n);
    return n;
}

// Cheap sincos in REVOLUTIONS: v_fract + v_sin + v_cos.
DEV void fsincos(float rev, float* s, float* c) {
    float f = __builtin_amdgcn_fractf(rev);
    *s = __builtin_amdgcn_sinf(f);
    *c = __builtin_amdgcn_cosf(f);
}

__global__ __launch_bounds__(256, 2)
void qrnn_kernel(const float* __restrict__ inputs, const float* __restrict__ initial_t,
                 const float* __restrict__ p1, const float* __restrict__ p2,
                 const float* __restrict__ kbw, const float* __restrict__ ksw,
                 const float* __restrict__ w1, const float* __restrict__ cb1,
                 const float* __restrict__ w2, const float* __restrict__ cb2,
                 float* __restrict__ out, int B, int S)
{
    // 8 lanes/slot, ONE element per thread -> B*8 threads = 512 blocks
    // = 2 waves/SIMD. Per gate: A1's partner goes through ds_swizzle (issued
    // first, LDS pipe), A0's partner through DPP (VALU) so gup(A0) issues
    // immediately and covers ~36 cyc of the swizzle's ~120 cyc latency;
    // the second resident wave covers the rest.
    // lane bit0->stored q2, bit1->stored q3, bit3->stored q1; bit2 = slot select.
    // CNOT rings are never applied: they are delayed as a pending linear frame Q
    // and folded into later gates' partner masks + Walsh sign constants.
    const int tid    = blockIdx.x * blockDim.x + threadIdx.x;
    const int lane16 = threadIdx.x & 15;
    const int e      = (tid >> 4) * 2 + ((lane16 >> 2) & 1);
    if (e >= B) return;
    const int sub    = lane16 & 3;
    const bool b1    = ((lane16 >> 3) & 1) != 0;
    const bool b2 = (sub & 1) != 0, b3 = (sub & 2) != 0;
    const float z2f = b2 ? -1.f : 1.f;
    const float z3f = b3 ? -1.f : 1.f;
    const float z1f = b1 ? -1.f : 1.f;
    const float z12 = z1f * z2f, z23 = z2f * z3f, z13 = z1f * z3f;
    const float z123 = z1f * z23;
    const bool is0 = (sub == 0), is1 = (sub == 1), is2 = (sub == 2);

    // Angles in REVOLUTIONS with -0.5 half-angle folded: stored = -rad/(4*pi).
    const float REVC = -0.07957747154594767f;   // -1/(4*pi)

    // ---- one-time: 16 base Rot matrices (input-constant)
    float u00r[4][4], u00i[4][4], u01r[4][4], u01i[4][4];
    const float* PP[2] = { p1, p2 };
#pragma unroll
    for (int aI = 0; aI < 2; ++aI) {
        const float* pp = PP[aI];
#pragma unroll
        for (int l = 0; l < 2; ++l) {
            const int idx = aI*2 + l;
#pragma unroll
            for (int q = 0; q < 4; ++q) {
                float phi = pp[l*12 + q*3 + 0];
                float tht = pp[l*12 + q*3 + 1];
                float omg = pp[l*12 + q*3 + 2];
                float st, ct; sincosf(0.5f*tht, &st, &ct);
                float sA, cA, sB, cB;
                sincosf(0.5f*(phi + omg), &sA, &cA);
                sincosf(0.5f*(phi - omg), &sB, &cB);
                u00r[idx][q] = rfl( cA*ct); u00i[idx][q] = rfl(-sA*ct);
                u01r[idx][q] = rfl(-cB*st); u01i[idx][q] = rfl(-sB*st);
            }
        }
    }

    // idx0: ansatz1 layer1, frame I (identical to verified baseline gates)
    const float Sr0 = u00r[0][0], Tr0 = u01r[0][0];
    const v2 Sin0 = (v2){-u00i[0][0], u00i[0][0]};
    const v2 Tin0 = (v2){-u01i[0][0], u01i[0][0]};
    float U0r[3], B0r[3]; v2 A0n[3], W0n[3];
    {
        const float zq3[3] = { z1f, z2f, z3f };
#pragma unroll
        for (int q = 1; q < 4; ++q) {
            float z = zq3[q-1];
            U0r[q-1] = u00r[0][q];
            A0n[q-1] = (v2){-z*u00i[0][q], z*u00i[0][q]};
            B0r[q-1] = z*u01r[0][q];
            W0n[q-1] = (v2){-u01i[0][q], u01i[0][q]};
        }
    }
    // idx1: V = H*U (unscaled, det -1: [[a,b],[b~,-a~]]), frame Q1 = R.
    // masks: q0:{n0,n1} q1:{n1,n2} q2:{n2,n3} q3:{n0,n1,n3}
    // sigma: {z123, n0*z1, n0*z12, n0*z123}  (det-1 fold: sigma on diag-REAL & off-IMAG)
    float d1r[4], o1r[4]; v2 d1i[4], o1i[4];
    {
        const float zf1[4] = { z123, z1f, z12, z123 };
#pragma unroll
        for (int q = 0; q < 4; ++q) {
            float ar = u00r[1][q] - u01r[1][q];
            float ai = u00i[1][q] + u01i[1][q];
            float br = u00r[1][q] + u01r[1][q];
            float bi = u01i[1][q] - u00i[1][q];
            float z = zf1[q];
            d1r[q] = z*ar;
            d1i[q] = (v2){-ai, ai};
            o1r[q] = br;
            o1i[q] = (v2){-z*bi, z*bi};
        }
    }
    // idx2: ansatz2 layer1 (det +1), frame Q2. masks: q0:{n0} q1:{n0,n2} q2:{n0,n3} q3:{n1}
    // sigma: {n0*z23, z2, z3, z1}  (det+1 fold: sigma on diag-IMAG & off-REAL)
    float s2r[4], t2r[4]; v2 s2i[4], t2i[4];
    {
        const float zf2[4] = { z23, z2f, z3f, z1f };
#pragma unroll
        for (int q = 0; q < 4; ++q) {
            float z = zf2[q];
            s2r[q] = u00r[2][q];
            s2i[q] = (v2){-z*u00i[2][q], z*u00i[2][q]};
            t2r[q] = z*u01r[2][q];
            t2i[q] = (v2){-u01i[2][q], u01i[2][q]};
        }
    }
    // idx3: ansatz2 layer2, frame Q3. masks: q0:{n2} q1:{n2,n3} q2:{n0,n1,n3} q3:{n1,n2}
    // sigma: {z123, n0*z3, n0, n0*z1}
    float s3r[4], t3r[4]; v2 s3i[4], t3i[4];
    {
        const float zf3[4] = { z123, z3f, 1.0f, z1f };
#pragma unroll
        for (int q = 0; q < 4; ++q) {
            float z = zf3[q];
            s3r[q] = u00r[3][q];
            s3i[q] = (v2){-z*u00i[3][q], z*u00i[3][q]};
            t3r[q] = z*u01r[3][q];
            t3i[q] = (v2){-u01i[3][q], u01i[3][q]};
        }
    }

    // ---- KAN cubic coeffs (lane 'sub' = input dim); REVC folded.
    float kQ0[7], kQ1[7], kQ2[7], kQ3[7], kBW[7];
#pragma unroll
    for (int r = 0; r < 7; ++r) {
        float sw0 = ksw[r*16 + sub*4 + 0], sw1 = ksw[r*16 + sub*4 + 1];
        float sw2 = ksw[r*16 + sub*4 + 2], sw3 = ksw[r*16 + sub*4 + 3];
        const float f = REVC / 48.0f;
        kQ0[r] = f * (sw0 + 23.f*sw1 + 23.f*sw2 + sw3);
        kQ1[r] = f * (-3.f*sw0 - 15.f*sw1 + 15.f*sw2 + 3.f*sw3);
        kQ2[r] = f * (3.f*sw0 - 3.f*sw1 - 3.f*sw2 + 3.f*sw3);
        kQ3[r] = f * (-sw0 + 3.f*sw1 - 3.f*sw2 + sw3);
        kBW[r] = REVC * kbw[r*4 + sub];
    }
    const int pr0[3] = {0, 1, 3}, pr1[3] = {4, 2, 6};
    v2 Q0p[3], Q1p[3], Q2p[3], Q3p[3], BWp[3];
#pragma unroll
    for (int j = 0; j < 3; ++j) {
        Q0p[j] = (v2){kQ0[pr0[j]], kQ0[pr1[j]]};
        Q1p[j] = (v2){kQ1[pr0[j]], kQ1[pr1[j]]};
        Q2p[j] = (v2){kQ2[pr0[j]], kQ2[pr1[j]]};
        Q3p[j] = (v2){kQ3[pr0[j]], kQ3[pr1[j]]};
        BWp[j] = (v2){kBW[pr0[j]], kBW[pr1[j]]};
    }

    // measurement: residual Walsh-strip + /256 folded into one per-lane scale
    // EV0=sum z1z3*dl, EV1=sum z1z2*dl, EV2=sum z1z2*s, EV3=sum z2*dl
    const float SCL = (is0 ? z13 : (is1 ? z12 : (is2 ? z12 : z2f))) * (1.0f/256.0f);

    // ---- per-element state: hidden pairs + inputs
    v2 H04, H12, H36;
    float H5;
    const float4* inp4 = (const float4*)inputs;
    H04 = (v2){REVC*initial_t[e*7+0], REVC*initial_t[e*7+4]};
    H12 = (v2){REVC*initial_t[e*7+1], REVC*initial_t[e*7+2]};
    H36 = (v2){REVC*initial_t[e*7+3], REVC*initial_t[e*7+6]};
    H5  = REVC*initial_t[e*7+5];
    const long BASE = (long)e * S;
    float4 XC = inp4[BASE];

    const float NQPI = -0.7853981633974483f;   // -pi/4
    float XK = 0.f;
    v2 A0, A1;

#pragma unroll 1
    for (int t = 0; t < S; ++t) {
        const int tn = (t + 1 < S) ? t + 1 : S - 1;
        float4 XN = inp4[BASE + tn];

        // ---- fm(hidden) on |0000>: amp = e^{i*2pi*sig}  (frame I)
        {
            float base = H12.x * z1f;
            base = fmaf(H12.y, z2f, base);
            base = fmaf(H36.x, z3f, base);
            base = fmaf(H5,   z12, base);
            base = fmaf(H36.y, z23, base);
            float w = fmaf(H04.y, z1f, H04.x);
            float s0, c0, s1, c1;
            fsincos(base + w, &s0, &c0);
            fsincos(base - w, &s1, &c1);
            A0 = (v2){c0, s0};
            A1 = (v2){c1, s1};
        }

        // ======== L0: ansatz1 layer1 (frame I). Ring R1 delayed. ========
        {   // q0: local pair
            v2 n0 = gup(A0, A1, Sr0,  Sin0,  Tr0, Tin0);
            v2 n1 = gup(A1, A0, Sr0, -Sin0, -Tr0, Tin0);
            A0 = n0; A1 = n1;
        }
        {   // q1: mask n1 (xor8), sigma z1 — swz(A1) first, DPP for A0
            v2 p1 = dswzv<8>(A1);
            A0 = gup(A0, ror8v(A0), U0r[0], A0n[0], B0r[0], W0n[0]);
            A1 = gup(A1, p1,        U0r[0], A0n[0], B0r[0], W0n[0]);
        }
        {   // q2: mask n2 (xor1), sigma z2
            v2 p1 = dswzv<1>(A1);
            A0 = gup(A0, lx1v(A0), U0r[1], A0n[1], B0r[1], W0n[1]);
            A1 = gup(A1, p1,       U0r[1], A0n[1], B0r[1], W0n[1]);
        }
        {   // q3: mask n3 (xor2), sigma z3
            v2 p1 = dswzv<2>(A1);
            A0 = gup(A0, lx2v(A0), U0r[2], A0n[2], B0r[2], W0n[2]);
            A1 = gup(A1, p1,       U0r[2], A0n[2], B0r[2], W0n[2]);
        }

        // ======== L1': H-folded ansatz1 layer2 (det -1), frame Q1 ========
        {   // g0: mask {n0,n1}: partner=xor8(other); sigma z123 (same both)
            v2 p1 = dswzv<8>(A0);
            v2 p0 = ror8v(A1);
            v2 n0 = gup(A0, p0, d1r[0], d1i[0], o1r[0], o1i[0]);
            v2 n1 = gup(A1, p1, d1r[0], d1i[0], o1r[0], o1i[0]);
            A0 = n0; A1 = n1;
        }
        {   // g1: mask {n1,n2}: xor9 same-reg; sigma n0*z1 -> A1 negs (dr,oi)
            v2 p1 = dswzv<9>(A1);
            A0 = gup(A0, r8lx1v(A0),  d1r[1], d1i[1], o1r[1],  o1i[1]);
            A1 = gup(A1, p1,         -d1r[1], d1i[1], o1r[1], -o1i[1]);
        }
        {   // g2: mask {n2,n3}: xor3; sigma n0*z12
            v2 p1 = dswzv<3>(A1);
            A0 = gup(A0, x3v(A0),  d1r[2], d1i[2], o1r[2],  o1i[2]);
            A1 = gup(A1, p1,      -d1r[2], d1i[2], o1r[2], -o1i[2]);
        }
        {   // g3: mask {n0,n1,n3}: partner=xor10(other); sigma n0*z123
            v2 p1 = dswzv<10>(A0);
            v2 p0 = r8lx2v(A1);
            v2 n0 = gup(A0, p0,  d1r[3], d1i[3], o1r[3],  o1i[3]);
            v2 n1 = gup(A1, p1, -d1r[3], d1i[3], o1r[3], -o1i[3]);
            A0 = n0; A1 = n1;
        }

        // ======== Phase_x (diag), frame Q2: Z0->n0*z23, Z1->z2, Z2->z3, Z3->z1,
        //          Z0Z1->n0*z3, Z1Z2->z23, Z2Z3->z13 ========
        {
            float hx0 = REVC*XC.x, hx1 = REVC*XC.y;
            float hx2 = REVC*XC.z, hx3 = REVC*XC.w;
            float u0 = fmaf(4.f, hx0, 1.f);
            float u1 = fmaf(4.f, hx1, 1.f);
            float u2 = fmaf(4.f, hx2, 1.f);
            float u3 = fmaf(4.f, hx3, 1.f);
            float he4 = NQPI * (u0*u1);
            float he5 = NQPI * (u1*u2);
            float he6 = NQPI * (u2*u3);

            float base = hx1 * z2f;
            base = fmaf(hx2, z3f, base);
            base = fmaf(hx3, z1f, base);
            base = fmaf(he5, z23, base);
            base = fmaf(he6, z13, base);
            float w = fmaf(he4, z3f, hx0 * z23);
            float s0, c0, s1, c1;
            fsincos(base + w, &s0, &c0);
            fsincos(base - w, &s1, &c1);
            v2 sn0 = (v2){-s0, s0};
            v2 sn1 = (v2){-s1, s1};
            A0 = vfma(vswap(A0), sn0, A0 * c0);
            A1 = vfma(vswap(A1), sn1, A1 * c1);
        }

        // ======== L2: ansatz2 layer1 (det +1), frame Q2 ========
        {   // g0: mask {n0} local; sigma n0*z23 -> A1 negs (di,orr)
            v2 n0 = gup(A0, A1, s2r[0],  s2i[0],  t2r[0], t2i[0]);
            v2 n1 = gup(A1, A0, s2r[0], -s2i[0], -t2r[0], t2i[0]);
            A0 = n0; A1 = n1;
        }
        {   // g1: mask {n0,n2}: partner=xor1(other); sigma z2 (same)
            v2 p1 = dswzv<1>(A0);
            v2 p0 = lx1v(A1);
            v2 n0 = gup(A0, p0, s2r[1], s2i[1], t2r[1], t2i[1]);
            v2 n1 = gup(A1, p1, s2r[1], s2i[1], t2r[1], t2i[1]);
            A0 = n0; A1 = n1;
        }
        {   // g2: mask {n0,n3}: partner=xor2(other); sigma z3 (same)
            v2 p1 = dswzv<2>(A0);
            v2 p0 = lx2v(A1);
            v2 n0 = gup(A0, p0, s2r[2], s2i[2], t2r[2], t2i[2]);
            v2 n1 = gup(A1, p1, s2r[2], s2i[2], t2r[2], t2i[2]);
            A0 = n0; A1 = n1;
        }
        {   // g3: mask {n1}: xor8 same; sigma z1 (same)
            v2 p1 = dswzv<8>(A1);
            A0 = gup(A0, ror8v(A0), s2r[3], s2i[3], t2r[3], t2i[3]);
            A1 = gup(A1, p1,        s2r[3], s2i[3], t2r[3], t2i[3]);
        }

        // ======== L3: ansatz2 layer2 (det +1), frame Q3 ========
        {   // g0: mask {n2}: xor1 same; sigma z123 (same)
            v2 p1 = dswzv<1>(A1);
            A0 = gup(A0, lx1v(A0), s3r[0], s3i[0], t3r[0], t3i[0]);
            A1 = gup(A1, p1,       s3r[0], s3i[0], t3r[0], t3i[0]);
        }
        {   // g1: mask {n2,n3}: xor3; sigma n0*z3 -> A1 negs
            v2 p1 = dswzv<3>(A1);
            A0 = gup(A0, x3v(A0),  s3r[1],  s3i[1],  t3r[1], t3i[1]);
            A1 = gup(A1, p1,       s3r[1], -s3i[1], -t3r[1], t3i[1]);
        }
        {   // g2: mask {n0,n1,n3}: partner=xor10(other); sigma n0
            v2 p1 = dswzv<10>(A0);
            v2 p0 = r8lx2v(A1);
            v2 n0 = gup(A0, p0, s3r[2],  s3i[2],  t3r[2], t3i[2]);
            v2 n1 = gup(A1, p1, s3r[2], -s3i[2], -t3r[2], t3i[2]);
            A0 = n0; A1 = n1;
        }
        {   // g3: mask {n1,n2}: xor9 same; sigma n0*z1 -> A1 negs
            v2 p1 = dswzv<9>(A1);
            A0 = gup(A0, r8lx1v(A0), s3r[3],  s3i[3],  t3r[3], t3i[3]);
            A1 = gup(A1, p1,         s3r[3], -s3i[3], -t3r[3], t3i[3]);
        }

        // ---- measurement, frame Q4 folded into Walsh butterflies (probs x256)
        {
            v2 m0 = A0 * A0, m1 = A1 * A1;
            float pa = m0.x + m0.y;
            float pb = m1.x + m1.y;
            float s  = pa + pb;
            float dl = pa - pb;
            float rd = ror8(dl);
            float tA = dl - rd;                    // antisym b3
            float vA = dl + rd;                    // sym b3
            float t1 = tA - lx1(tA); t1 += lx2(t1);  // z1z2*EV1
            float t0 = tA + lx1(tA); t0 -= lx2(t0);  // z1z3*EV0
            float v1 = vA - lx1(vA); v1 += lx2(v1);  // z2*EV3
            float wA = s - ror8(s);
            float w1m = wA - lx1(wA); w1m += lx2(w1m);  // z1z2*EV2
            float pre = is0 ? t0 : (is1 ? t1 : (is2 ? w1m : v1));
            XK = pre * SCL;
        }

        // ---- KAN (packed pairs): lane sub = input dim; quad-reduce sums dims
        {
            float xk = XK;
            float eneg = __builtin_amdgcn_exp2f(xk * -1.44269504088896f);
            float silu = xk * __builtin_amdgcn_rcpf(1.0f + eneg);
            v2 xs = vsplat(xk), ss = vsplat(silu);
            v2 op[3];
#pragma unroll
            for (int k = 0; k < 3; ++k) {
                v2 o = vfma(Q3p[k], xs, Q2p[k]);
                o = vfma(o, xs, Q1p[k]);
                o = vfma(o, xs, Q0p[k]);
                o = vfma(BWp[k], ss, o);
                o = o + (v2){lx1(o.x), lx1(o.y)};
                o = o + (v2){lx2(o.x), lx2(o.y)};
                op[k] = o;
            }
            {   // scalar r=5
                float o = fmaf(kQ3[5], xk, kQ2[5]);
                o = fmaf(o, xk, kQ1[5]);
                o = fmaf(o, xk, kQ0[5]);
                o = fmaf(kBW[5], silu, o);
                o += lx1(o); o += lx2(o);
                H5 = o;
            }
            H04 = op[0]; H12 = op[1]; H36 = op[2];
            XC = XN;
        }
    }

    // ---- classifier head: quad lanes hold ev0..ev3 per element
    {
        float xk  = XK;
        float ev1 = qperm<0x55>(xk);
        float ev2 = qperm<0xAA>(xk);
        float ev3 = qperm<0xFF>(xk);
        if (sub == 0 && !b1) {
            float acc = cb2[0];
#pragma unroll
            for (int i = 0; i < 16; ++i) {
                float h = cb1[i] + w1[i*4+0]*xk + w1[i*4+1]*ev1
                        + w1[i*4+2]*ev2 + w1[i*4+3]*ev3;
                h = fmaxf(h, 0.0f);
                acc += w2[i]*h;
            }
            out[e] = acc;
        }
    }
}

extern "C" void kernel_launch(void* const* d_in, const int* in_sizes, int n_in,
                              void* d_out, int out_size, void* d_ws, size_t ws_size,
                              hipStream_t stream) {
    const float* inputs    = (const float*)d_in[0];
    const float* initial_t = (const float*)d_in[1];
    const float* p1        = (const float*)d_in[2];
    const float* p2        = (const float*)d_in[3];
    const float* kbw       = (const float*)d_in[4];
    const float* ksw       = (const float*)d_in[5];
    const float* w1        = (const float*)d_in[6];
    const float* cb1       = (const float*)d_in[7];
    const float* w2        = (const float*)d_in[8];
    const float* cb2       = (const float*)d_in[9];

    const int B = in_sizes[1] / 7;            // 16384
    const int S = in_sizes[0] / (B * 4);      // 256

    const int threads = B * 8;                // 8 lanes/slot, 1 element/thread
    const int block = 256;
    const int grid = (threads + block - 1) / block;   // 512 blocks -> 2 waves/SIMD

    qrnn_kernel<<<grid, block, 0, stream>>>(inputs, initial_t, p1, p2, kbw, ksw,
                                            w1, cb1, w2, cb2, (float*)d_out, B, S);
}

// Round 6
// 282.082 us; speedup vs baseline: 1.2797x; 1.0600x over previous
//
#include <hip/hip_runtime.h>
#include <math.h>

#define DEV static __device__ __forceinline__

typedef float v2 __attribute__((ext_vector_type(2)));

// Quad-perm DPP — full-rate VALU, 1-2 cyc forwarding. ALL cross-lane traffic
// in this layout is quad-local (lane bits 0-1 = qubits n2,n3), so no LDS pipe
// and no ds_swizzle latency anywhere.
template<int CTRL>
DEV float qperm(float x) {
    return __int_as_float(__builtin_amdgcn_mov_dpp(__float_as_int(x), CTRL, 0xF, 0xF, true));
}
DEV float lx1(float v)  { return qperm<0xB1>(v); }   // xor lane bit0 (n2)
DEV float lx2(float v)  { return qperm<0x4E>(v); }   // xor lane bit1 (n3)
DEV float x3f_(float v) { return qperm<0x1B>(v); }   // xor both (n2,n3)
DEV float rfl(float x)  { return __int_as_float(__builtin_amdgcn_readfirstlane(__float_as_int(x))); }

DEV v2 lx1v(v2 a) { return (v2){lx1(a.x), lx1(a.y)}; }
DEV v2 lx2v(v2 a) { return (v2){lx2(a.x), lx2(a.y)}; }
DEV v2 x3v(v2 a)  { return (v2){x3f_(a.x), x3f_(a.y)}; }

// masked-rot update with SCALAR complex coefficients:
//   n = (dr + i*di) * A + (orr + i*oi) * P     (sign variants via free VOP3 negs)
DEV v2 gup_s(v2 A, v2 P, float dr, float di, float orr, float oi) {
    v2 n;
    n.x = A.x*dr; n.x = fmaf(A.y, -di, n.x); n.x = fmaf(P.x, orr, n.x); n.x = fmaf(P.y, -oi, n.x);
    n.y = A.y*dr; n.y = fmaf(A.x,  di, n.y); n.y = fmaf(P.y, orr, n.y); n.y = fmaf(P.x,  oi, n.y);
    return n;
}
// diagonal phase: A *= (c + i*s)
DEV v2 prot(v2 A, float c, float s) {
    v2 n;
    n.x = A.x*c; n.x = fmaf(A.y, -s, n.x);
    n.y = A.y*c; n.y = fmaf(A.x,  s, n.y);
    return n;
}

// Cheap sincos in REVOLUTIONS: v_fract + v_sin + v_cos.
DEV void fsincos(float rev, float* s, float* c) {
    float f = __builtin_amdgcn_fractf(rev);
    *s = __builtin_amdgcn_sinf(f);
    *c = __builtin_amdgcn_cosf(f);
}

__global__ __launch_bounds__(256, 1)
void qrnn_kernel(const float* __restrict__ inputs, const float* __restrict__ initial_t,
                 const float* __restrict__ p1, const float* __restrict__ p2,
                 const float* __restrict__ kbw, const float* __restrict__ ksw,
                 const float* __restrict__ w1, const float* __restrict__ cb1,
                 const float* __restrict__ w2, const float* __restrict__ cb2,
                 float* __restrict__ out, int B, int S)
{
    // 4-lane layout: lane bit0->n2, bit1->n3; n0,n1 live IN REGISTERS:
    // each thread holds a[n0][n1] (4 complex amps). 4 lanes = 1 element,
    // wave = 16 elements -> per-element cost of KAN/phase/measurement halves
    // vs the 8-lane layout, and every partner fetch is quad DPP or a register
    // rename. B*4 threads -> 256 blocks -> 1 wave/SIMD; 4 chains give ILP.
    // CNOT rings are never applied (frame-tracking, verified in the 8-lane
    // kernel): old lane-z1 signs -> per-chain eps1 negations; old A0/A1-row
    // negations -> per-chain eps0 negations; z2/z3 stay lane constants.
    const int tid = blockIdx.x * blockDim.x + threadIdx.x;
    const int e   = tid >> 2;
    if (e >= B) return;
    const int sub = threadIdx.x & 3;
    const bool b2 = (sub & 1) != 0, b3 = (sub & 2) != 0;
    const float z2f = b2 ? -1.f : 1.f;
    const float z3f = b3 ? -1.f : 1.f;
    const float z23 = z2f * z3f;
    const bool is0 = (sub == 0), is1 = (sub == 1), is2 = (sub == 2);

    // Angles in REVOLUTIONS with -0.5 half-angle folded: stored = -rad/(4*pi).
    const float REVC = -0.07957747154594767f;   // -1/(4*pi)
    const float NQPI = -0.7853981633974483f;    // -pi/4

    // ---- one-time: 16 base Rot matrices (input-constant)
    float u00r[4][4], u00i[4][4], u01r[4][4], u01i[4][4];
    const float* PP[2] = { p1, p2 };
#pragma unroll
    for (int aI = 0; aI < 2; ++aI) {
        const float* pp = PP[aI];
#pragma unroll
        for (int l = 0; l < 2; ++l) {
            const int idx = aI*2 + l;
#pragma unroll
            for (int q = 0; q < 4; ++q) {
                float phi = pp[l*12 + q*3 + 0];
                float tht = pp[l*12 + q*3 + 1];
                float omg = pp[l*12 + q*3 + 2];
                float st, ct; sincosf(0.5f*tht, &st, &ct);
                float sA, cA, sB, cB;
                sincosf(0.5f*(phi + omg), &sA, &cA);
                sincosf(0.5f*(phi - omg), &sB, &cB);
                u00r[idx][q] = rfl( cA*ct); u00i[idx][q] = rfl(-sA*ct);
                u01r[idx][q] = rfl(-cB*st); u01i[idx][q] = rfl(-sB*st);
            }
        }
    }

    // ---- per-gate scalar coefficients {dr, di, orr, oi}, z2/z3 parts folded.
    // gates 0-3: L0 q0..q3; 4-7: L1' g0..g3 (det-1, sigma on dr&oi);
    // 8-11: L2 g0..g3 (det+1, sigma on di&orr); 12-15: L3 g0..g3.
    // Chain-sign (eps0/eps1) parts applied at call sites via negation.
    float cdr[16], cdi[16], cor_[16], coi[16];
    {
        const float f0[4] = {1.f, 1.f, z2f, z3f};          // L0 sigma: n0, n1, z2, z3
#pragma unroll
        for (int q = 0; q < 4; ++q) {
            cdr[q]  = u00r[0][q];
            cdi[q]  = f0[q]*u00i[0][q];
            cor_[q] = f0[q]*u01r[0][q];
            coi[q]  = u01i[0][q];
        }
        const float f1a[4] = {z23, 1.f, z2f, z23};         // L1' sigma z-parts
#pragma unroll
        for (int q = 0; q < 4; ++q) {
            float ar = u00r[1][q] - u01r[1][q];
            float ai = u00i[1][q] + u01i[1][q];
            float br = u00r[1][q] + u01r[1][q];
            float bi = u01i[1][q] - u00i[1][q];
            cdr[4+q]  = f1a[q]*ar;
            cdi[4+q]  = ai;
            cor_[4+q] = br;
            coi[4+q]  = f1a[q]*bi;
        }
        const float f2a[4] = {z23, z2f, z3f, 1.f};         // L2 sigma z-parts
#pragma unroll
        for (int q = 0; q < 4; ++q) {
            cdr[8+q]  = u00r[2][q];
            cdi[8+q]  = f2a[q]*u00i[2][q];
            cor_[8+q] = f2a[q]*u01r[2][q];
            coi[8+q]  = u01i[2][q];
        }
        const float f3a[4] = {z23, z3f, 1.f, 1.f};         // L3 sigma z-parts
#pragma unroll
        for (int q = 0; q < 4; ++q) {
            cdr[12+q]  = u00r[3][q];
            cdi[12+q]  = f3a[q]*u00i[3][q];
            cor_[12+q] = f3a[q]*u01r[3][q];
            coi[12+q]  = u01i[3][q];
        }
    }

    // ---- KAN cubic coeffs (lane 'sub' = input dim); REVC folded.
    float kQ0[7], kQ1[7], kQ2[7], kQ3[7], kBW[7];
#pragma unroll
    for (int r = 0; r < 7; ++r) {
        float sw0 = ksw[r*16 + sub*4 + 0], sw1 = ksw[r*16 + sub*4 + 1];
        float sw2 = ksw[r*16 + sub*4 + 2], sw3 = ksw[r*16 + sub*4 + 3];
        const float f = REVC / 48.0f;
        kQ0[r] = f * (sw0 + 23.f*sw1 + 23.f*sw2 + sw3);
        kQ1[r] = f * (-3.f*sw0 - 15.f*sw1 + 15.f*sw2 + 3.f*sw3);
        kQ2[r] = f * (3.f*sw0 - 3.f*sw1 - 3.f*sw2 + 3.f*sw3);
        kQ3[r] = f * (-sw0 + 3.f*sw1 - 3.f*sw2 + sw3);
        kBW[r] = REVC * kbw[r*4 + sub];
    }
    const int pr0[3] = {0, 1, 3}, pr1[3] = {4, 2, 6};
    v2 Q0p[3], Q1p[3], Q2p[3], Q3p[3], BWp[3];
#pragma unroll
    for (int j = 0; j < 3; ++j) {
        Q0p[j] = (v2){kQ0[pr0[j]], kQ0[pr1[j]]};
        Q1p[j] = (v2){kQ1[pr0[j]], kQ1[pr1[j]]};
        Q2p[j] = (v2){kQ2[pr0[j]], kQ2[pr1[j]]};
        Q3p[j] = (v2){kQ3[pr0[j]], kQ3[pr1[j]]};
        BWp[j] = (v2){kBW[pr0[j]], kBW[pr1[j]]};
    }

    // measurement residual sign + /256 (derivation in measurement block)
    const float SCL = (is0 ? z3f : z2f) * (1.0f/256.0f);
    const float zNQ3  = z3f * NQPI;
    const float zNQ23 = z23 * NQPI;

    // ---- per-element state
    v2 H04, H12, H36;
    float H5;
    const float4* inp4 = (const float4*)inputs;
    H04 = (v2){REVC*initial_t[e*7+0], REVC*initial_t[e*7+4]};
    H12 = (v2){REVC*initial_t[e*7+1], REVC*initial_t[e*7+2]};
    H36 = (v2){REVC*initial_t[e*7+3], REVC*initial_t[e*7+6]};
    H5  = REVC*initial_t[e*7+5];
    const long BASE = (long)e * S;
    float4 XC = inp4[BASE];

    float XK = 0.f;
    v2 a00, a01, a10, a11;   // a[n0][n1]

#pragma unroll 1
    for (int t = 0; t < S; ++t) {
        const int tn = (t + 1 < S) ? t + 1 : S - 1;
        float4 XN = inp4[BASE + tn];

        // ---- fm(hidden) on |0000>: sig(a,b) = c + e1*d + e0*(w0 + e1*w1)
        {
            float c_ = z2f*H12.y;
            c_ = fmaf(z3f, H36.x, c_);
            c_ = fmaf(z23, H36.y, c_);
            float d_ = fmaf(z2f, H5, H12.x);
            float w0 = H04.x, w1 = H04.y;
            float pd = c_ + d_, qd = c_ - d_;
            float rw = w0 + w1, sw = w0 - w1;
            float s00,c00,s01,c01,s10,c10,s11,c11;
            fsincos(pd + rw, &s00, &c00);
            fsincos(qd + sw, &s01, &c01);
            fsincos(pd - rw, &s10, &c10);
            fsincos(qd - sw, &s11, &c11);
            a00 = (v2){c00, s00}; a01 = (v2){c01, s01};
            a10 = (v2){c10, s10}; a11 = (v2){c11, s11};
        }

        // ======== L0: ansatz1 layer1 ========
        {   // q0: n0-pair; eps0 on (di,orr)
            v2 n00 = gup_s(a00, a10, cdr[0],  cdi[0],  cor_[0], coi[0]);
            v2 n10 = gup_s(a10, a00, cdr[0], -cdi[0], -cor_[0], coi[0]);
            v2 n01 = gup_s(a01, a11, cdr[0],  cdi[0],  cor_[0], coi[0]);
            v2 n11 = gup_s(a11, a01, cdr[0], -cdi[0], -cor_[0], coi[0]);
            a00=n00; a10=n10; a01=n01; a11=n11;
        }
        {   // q1: n1-pair; eps1 on (di,orr)
            v2 n00 = gup_s(a00, a01, cdr[1],  cdi[1],  cor_[1], coi[1]);
            v2 n01 = gup_s(a01, a00, cdr[1], -cdi[1], -cor_[1], coi[1]);
            v2 n10 = gup_s(a10, a11, cdr[1],  cdi[1],  cor_[1], coi[1]);
            v2 n11 = gup_s(a11, a10, cdr[1], -cdi[1], -cor_[1], coi[1]);
            a00=n00; a01=n01; a10=n10; a11=n11;
        }
        // q2: lx1 self; z2 in consts
        a00 = gup_s(a00, lx1v(a00), cdr[2], cdi[2], cor_[2], coi[2]);
        a01 = gup_s(a01, lx1v(a01), cdr[2], cdi[2], cor_[2], coi[2]);
        a10 = gup_s(a10, lx1v(a10), cdr[2], cdi[2], cor_[2], coi[2]);
        a11 = gup_s(a11, lx1v(a11), cdr[2], cdi[2], cor_[2], coi[2]);
        // q3: lx2 self; z3 in consts
        a00 = gup_s(a00, lx2v(a00), cdr[3], cdi[3], cor_[3], coi[3]);
        a01 = gup_s(a01, lx2v(a01), cdr[3], cdi[3], cor_[3], coi[3]);
        a10 = gup_s(a10, lx2v(a10), cdr[3], cdi[3], cor_[3], coi[3]);
        a11 = gup_s(a11, lx2v(a11), cdr[3], cdi[3], cor_[3], coi[3]);

        // ======== L1': H-folded ansatz1 layer2 (det -1; sigma on dr&oi) ========
        {   // g0: mask {n0,n1}: cross-pair; eps1 on (dr,oi)
            v2 n00 = gup_s(a00, a11,  cdr[4], cdi[4], cor_[4],  coi[4]);
            v2 n01 = gup_s(a01, a10, -cdr[4], cdi[4], cor_[4], -coi[4]);
            v2 n10 = gup_s(a10, a01,  cdr[4], cdi[4], cor_[4],  coi[4]);
            v2 n11 = gup_s(a11, a00, -cdr[4], cdi[4], cor_[4], -coi[4]);
            a00=n00; a01=n01; a10=n10; a11=n11;
        }
        {   // g1: mask {n1,n2}: n1-pair + lx1; eps0*eps1 on (dr,oi)
            v2 p00 = lx1v(a01), p01 = lx1v(a00), p10 = lx1v(a11), p11 = lx1v(a10);
            v2 n00 = gup_s(a00, p00,  cdr[5], cdi[5], cor_[5],  coi[5]);
            v2 n01 = gup_s(a01, p01, -cdr[5], cdi[5], cor_[5], -coi[5]);
            v2 n10 = gup_s(a10, p10, -cdr[5], cdi[5], cor_[5], -coi[5]);
            v2 n11 = gup_s(a11, p11,  cdr[5], cdi[5], cor_[5],  coi[5]);
            a00=n00; a01=n01; a10=n10; a11=n11;
        }
        // g2: mask {n2,n3}: x3 self; eps0*eps1 on (dr,oi)
        a00 = gup_s(a00, x3v(a00),  cdr[6], cdi[6], cor_[6],  coi[6]);
        a01 = gup_s(a01, x3v(a01), -cdr[6], cdi[6], cor_[6], -coi[6]);
        a10 = gup_s(a10, x3v(a10), -cdr[6], cdi[6], cor_[6], -coi[6]);
        a11 = gup_s(a11, x3v(a11),  cdr[6], cdi[6], cor_[6],  coi[6]);
        {   // g3: mask {n0,n1,n3}: cross-pair + lx2; eps0*eps1 on (dr,oi)
            v2 p00 = lx2v(a11), p01 = lx2v(a10), p10 = lx2v(a01), p11 = lx2v(a00);
            v2 n00 = gup_s(a00, p00,  cdr[7], cdi[7], cor_[7],  coi[7]);
            v2 n01 = gup_s(a01, p01, -cdr[7], cdi[7], cor_[7], -coi[7]);
            v2 n10 = gup_s(a10, p10, -cdr[7], cdi[7], cor_[7], -coi[7]);
            v2 n11 = gup_s(a11, p11,  cdr[7], cdi[7], cor_[7],  coi[7]);
            a00=n00; a01=n01; a10=n10; a11=n11;
        }

        // ======== Phase_x (diag), frame Q2: sig = c2 + e1*d2 + e0*w2 ========
        {
            float hx0 = REVC*XC.x, hx1 = REVC*XC.y;
            float hx2 = REVC*XC.z, hx3 = REVC*XC.w;
            float u0 = fmaf(4.f, hx0, 1.f);
            float u1 = fmaf(4.f, hx1, 1.f);
            float u2 = fmaf(4.f, hx2, 1.f);
            float u3 = fmaf(4.f, hx3, 1.f);
            float h4r = u0*u1, h5r = u1*u2, h6r = u2*u3;
            float c2 = z2f*hx1;
            c2 = fmaf(z3f, hx2, c2);
            c2 = fmaf(zNQ23, h5r, c2);
            float d2 = fmaf(zNQ3, h6r, hx3);
            float w2 = fmaf(zNQ3, h4r, z23*hx0);
            float p2 = c2 + d2, q2v = c2 - d2;
            float s00,c00,s01,c01,s10,c10,s11,c11;
            fsincos(p2 + w2,  &s00, &c00);
            fsincos(q2v + w2, &s01, &c01);
            fsincos(p2 - w2,  &s10, &c10);
            fsincos(q2v - w2, &s11, &c11);
            a00 = prot(a00, c00, s00);
            a01 = prot(a01, c01, s01);
            a10 = prot(a10, c10, s10);
            a11 = prot(a11, c11, s11);
        }

        // ======== L2: ansatz2 layer1 (det +1; sigma on di&orr) ========
        {   // g0: mask {n0}: n0-pair; eps0 on (di,orr)
            v2 n00 = gup_s(a00, a10, cdr[8],  cdi[8],  cor_[8], coi[8]);
            v2 n10 = gup_s(a10, a00, cdr[8], -cdi[8], -cor_[8], coi[8]);
            v2 n01 = gup_s(a01, a11, cdr[8],  cdi[8],  cor_[8], coi[8]);
            v2 n11 = gup_s(a11, a01, cdr[8], -cdi[8], -cor_[8], coi[8]);
            a00=n00; a10=n10; a01=n01; a11=n11;
        }
        {   // g1: mask {n0,n2}: n0-pair + lx1; no chain signs (z2 in consts)
            v2 p00 = lx1v(a10), p10 = lx1v(a00), p01 = lx1v(a11), p11 = lx1v(a01);
            v2 n00 = gup_s(a00, p00, cdr[9], cdi[9], cor_[9], coi[9]);
            v2 n10 = gup_s(a10, p10, cdr[9], cdi[9], cor_[9], coi[9]);
            v2 n01 = gup_s(a01, p01, cdr[9], cdi[9], cor_[9], coi[9]);
            v2 n11 = gup_s(a11, p11, cdr[9], cdi[9], cor_[9], coi[9]);
            a00=n00; a10=n10; a01=n01; a11=n11;
        }
        {   // g2: mask {n0,n3}: n0-pair + lx2; no chain signs (z3 in consts)
            v2 p00 = lx2v(a10), p10 = lx2v(a00), p01 = lx2v(a11), p11 = lx2v(a01);
            v2 n00 = gup_s(a00, p00, cdr[10], cdi[10], cor_[10], coi[10]);
            v2 n10 = gup_s(a10, p10, cdr[10], cdi[10], cor_[10], coi[10]);
            v2 n01 = gup_s(a01, p01, cdr[10], cdi[10], cor_[10], coi[10]);
            v2 n11 = gup_s(a11, p11, cdr[10], cdi[10], cor_[10], coi[10]);
            a00=n00; a10=n10; a01=n01; a11=n11;
        }
        {   // g3: mask {n1}: n1-pair; eps1 on (di,orr)
            v2 n00 = gup_s(a00, a01, cdr[11],  cdi[11],  cor_[11], coi[11]);
            v2 n01 = gup_s(a01, a00, cdr[11], -cdi[11], -cor_[11], coi[11]);
            v2 n10 = gup_s(a10, a11, cdr[11],  cdi[11],  cor_[11], coi[11]);
            v2 n11 = gup_s(a11, a10, cdr[11], -cdi[11], -cor_[11], coi[11]);
            a00=n00; a01=n01; a10=n10; a11=n11;
        }

        // ======== L3: ansatz2 layer2 (det +1; sigma on di&orr) ========
        // g0: mask {n2}: lx1 self; eps1 on (di,orr), z23 in consts
        a00 = gup_s(a00, lx1v(a00), cdr[12],  cdi[12],  cor_[12], coi[12]);
        a01 = gup_s(a01, lx1v(a01), cdr[12], -cdi[12], -cor_[12], coi[12]);
        a10 = gup_s(a10, lx1v(a10), cdr[12],  cdi[12],  cor_[12], coi[12]);
        a11 = gup_s(a11, lx1v(a11), cdr[12], -cdi[12], -cor_[12], coi[12]);
        // g1: mask {n2,n3}: x3 self; eps0 on (di,orr), z3 in consts
        a00 = gup_s(a00, x3v(a00), cdr[13],  cdi[13],  cor_[13], coi[13]);
        a01 = gup_s(a01, x3v(a01), cdr[13],  cdi[13],  cor_[13], coi[13]);
        a10 = gup_s(a10, x3v(a10), cdr[13], -cdi[13], -cor_[13], coi[13]);
        a11 = gup_s(a11, x3v(a11), cdr[13], -cdi[13], -cor_[13], coi[13]);
        {   // g2: mask {n0,n1,n3}: cross-pair + lx2; eps0 on (di,orr)
            v2 p00 = lx2v(a11), p01 = lx2v(a10), p10 = lx2v(a01), p11 = lx2v(a00);
            v2 n00 = gup_s(a00, p00, cdr[14],  cdi[14],  cor_[14], coi[14]);
            v2 n01 = gup_s(a01, p01, cdr[14],  cdi[14],  cor_[14], coi[14]);
            v2 n10 = gup_s(a10, p10, cdr[14], -cdi[14], -cor_[14], coi[14]);
            v2 n11 = gup_s(a11, p11, cdr[14], -cdi[14], -cor_[14], coi[14]);
            a00=n00; a01=n01; a10=n10; a11=n11;
        }
        {   // g3: mask {n1,n2}: n1-pair + lx1; eps0*eps1 on (di,orr)
            v2 p00 = lx1v(a01), p01 = lx1v(a00), p10 = lx1v(a11), p11 = lx1v(a10);
            v2 n00 = gup_s(a00, p00, cdr[15],  cdi[15],  cor_[15], coi[15]);
            v2 n01 = gup_s(a01, p01, cdr[15], -cdi[15], -cor_[15], coi[15]);
            v2 n10 = gup_s(a10, p10, cdr[15], -cdi[15], -cor_[15], coi[15]);
            v2 n11 = gup_s(a11, p11, cdr[15],  cdi[15],  cor_[15], coi[15]);
            a00=n00; a01=n01; a10=n10; a11=n11;
        }

        // ---- measurement (Walsh over n0,n1 in-register; n2,n3 quad DPP)
        // EV0 = sum(-1)^{n0+n1+n3}p, EV1 = sum(-1)^{n0+n1+n2}p,
        // EV2 = sum(-1)^{n1+n2}p,    EV3 = sum(-1)^{n0+n2}p   (probs x256)
        {
            float m00 = fmaf(a00.y, a00.y, a00.x*a00.x);
            float m01 = fmaf(a01.y, a01.y, a01.x*a01.x);
            float m10 = fmaf(a10.y, a10.y, a10.x*a10.x);
            float m11 = fmaf(a11.y, a11.y, a11.x*a11.x);
            float g_ = m00 - m01, h_ = m10 - m11;
            float dl01 = g_ - h_;                         // (-1)^{n0^n1}
            float sn1  = g_ + h_;                         // (-1)^{n1}
            float dn0  = (m00 + m01) - (m10 + m11);       // (-1)^{n0}
            float l1a = lx1(dl01);
            float up = dl01 + l1a;
            float um = dl01 - l1a;
            float t0 = up - lx2(up);                      // z3f * EV0*256
            float t1 = um + lx2(um);                      // z2f * EV1*256
            float vm = sn1 - lx1(sn1);
            float t2 = vm + lx2(vm);                      // z2f * EV2*256
            float wm = dn0 - lx1(dn0);
            float t3 = wm + lx2(wm);                      // z2f * EV3*256
            float pre = is0 ? t0 : (is1 ? t1 : (is2 ? t2 : t3));
            XK = pre * SCL;
        }

        // ---- KAN (packed pairs): lane sub = input dim; quad-reduce sums dims
        {
            float xk = XK;
            float eneg = __builtin_amdgcn_exp2f(xk * -1.44269504088896f);
            float silu = xk * __builtin_amdgcn_rcpf(1.0f + eneg);
            v2 xs = (v2){xk, xk}, ss = (v2){silu, silu};
            v2 op[3];
#pragma unroll
            for (int k = 0; k < 3; ++k) {
                v2 o = __builtin_elementwise_fma(Q3p[k], xs, Q2p[k]);
                o = __builtin_elementwise_fma(o, xs, Q1p[k]);
                o = __builtin_elementwise_fma(o, xs, Q0p[k]);
                o = __builtin_elementwise_fma(BWp[k], ss, o);
                o = o + (v2){lx1(o.x), lx1(o.y)};
                o = o + (v2){lx2(o.x), lx2(o.y)};
                op[k] = o;
            }
            {   // scalar r=5
                float o = fmaf(kQ3[5], xk, kQ2[5]);
                o = fmaf(o, xk, kQ1[5]);
                o = fmaf(o, xk, kQ0[5]);
                o = fmaf(kBW[5], silu, o);
                o += lx1(o); o += lx2(o);
                H5 = o;
            }
            H04 = op[0]; H12 = op[1]; H36 = op[2];
            XC = XN;
        }
    }

    // ---- classifier head: quad lanes hold ev0..ev3 per element
    {
        float xk  = XK;
        float ev1 = qperm<0x55>(xk);
        float ev2 = qperm<0xAA>(xk);
        float ev3 = qperm<0xFF>(xk);
        if (is0) {
            float acc = cb2[0];
#pragma unroll
            for (int i = 0; i < 16; ++i) {
                float h = cb1[i] + w1[i*4+0]*xk + w1[i*4+1]*ev1
                        + w1[i*4+2]*ev2 + w1[i*4+3]*ev3;
                h = fmaxf(h, 0.0f);
                acc += w2[i]*h;
            }
            out[e] = acc;
        }
    }
}

extern "C" void kernel_launch(void* const* d_in, const int* in_sizes, int n_in,
                              void* d_out, int out_size, void* d_ws, size_t ws_size,
                              hipStream_t stream) {
    const float* inputs    = (const float*)d_in[0];
    const float* initial_t = (const float*)d_in[1];
    const float* p1        = (const float*)d_in[2];
    const float* p2        = (const float*)d_in[3];
    const float* kbw       = (const float*)d_in[4];
    const float* ksw       = (const float*)d_in[5];
    const float* w1        = (const float*)d_in[6];
    const float* cb1       = (const float*)d_in[7];
    const float* w2        = (const float*)d_in[8];
    const float* cb2       = (const float*)d_in[9];

    const int B = in_sizes[1] / 7;            // 16384
    const int S = in_sizes[0] / (B * 4);      // 256

    const int threads = B * 4;                // 4 lanes/element, 1 element/thread
    const int block = 256;
    const int grid = (threads + block - 1) / block;   // 256 blocks -> 1 wave/SIMD

    qrnn_kernel<<<grid, block, 0, stream>>>(inputs, initial_t, p1, p2, kbw, ksw,
                                            w1, cb1, w2, cb2, (float*)d_out, B, S);
}

// Round 7
// 280.555 us; speedup vs baseline: 1.2866x; 1.0054x over previous
//
#include <hip/hip_runtime.h>
#include <math.h>

#define DEV static __device__ __forceinline__

typedef float v2 __attribute__((ext_vector_type(2)));

// Quad-perm DPP — full-rate VALU, 1-2 cyc forwarding. ALL cross-lane traffic
// in this layout is quad-local (lane bits 0-1 = qubits n2,n3), so no LDS pipe
// and no ds_swizzle latency anywhere.
template<int CTRL>
DEV float qperm(float x) {
    return __int_as_float(__builtin_amdgcn_mov_dpp(__float_as_int(x), CTRL, 0xF, 0xF, true));
}
DEV float lx1(float v)  { return qperm<0xB1>(v); }   // xor lane bit0 (n2)
DEV float lx2(float v)  { return qperm<0x4E>(v); }   // xor lane bit1 (n3)
DEV float x3f_(float v) { return qperm<0x1B>(v); }   // xor both (n2,n3)
DEV float rfl(float x)  { return __int_as_float(__builtin_amdgcn_readfirstlane(__float_as_int(x))); }

DEV v2 lx1v(v2 a) { return (v2){lx1(a.x), lx1(a.y)}; }
DEV v2 lx2v(v2 a) { return (v2){lx2(a.x), lx2(a.y)}; }
DEV v2 x3v(v2 a)  { return (v2){x3f_(a.x), x3f_(a.y)}; }

// masked-rot update with SCALAR complex coefficients:
//   n = (dr + i*di) * A + (orr + i*oi) * P     (sign variants via free VOP3 negs)
DEV v2 gup_s(v2 A, v2 P, float dr, float di, float orr, float oi) {
    v2 n;
    n.x = A.x*dr; n.x = fmaf(A.y, -di, n.x); n.x = fmaf(P.x, orr, n.x); n.x = fmaf(P.y, -oi, n.x);
    n.y = A.y*dr; n.y = fmaf(A.x,  di, n.y); n.y = fmaf(P.y, orr, n.y); n.y = fmaf(P.x,  oi, n.y);
    return n;
}
// diagonal phase: A *= (c + i*s), pair packed as {c,s}
DEV v2 prot(v2 A, v2 cs) {
    v2 n;
    n.x = A.x*cs.x; n.x = fmaf(A.y, -cs.y, n.x);
    n.y = A.y*cs.x; n.y = fmaf(A.x,  cs.y, n.y);
    return n;
}

// Cheap sincos in REVOLUTIONS: v_fract + v_sin + v_cos.
DEV void fsincos(float rev, float* s, float* c) {
    float f = __builtin_amdgcn_fractf(rev);
    *s = __builtin_amdgcn_sinf(f);
    *c = __builtin_amdgcn_cosf(f);
}

__global__ __launch_bounds__(256, 1)
void qrnn_kernel(const float* __restrict__ inputs, const float* __restrict__ initial_t,
                 const float* __restrict__ p1, const float* __restrict__ p2,
                 const float* __restrict__ kbw, const float* __restrict__ ksw,
                 const float* __restrict__ w1, const float* __restrict__ cb1,
                 const float* __restrict__ w2, const float* __restrict__ cb2,
                 float* __restrict__ out, int B, int S)
{
    // 4-lane layout: lane bit0->n2, bit1->n3; n0,n1 live IN REGISTERS:
    // each thread holds a[n0][n1] (4 complex amps). 4 lanes = 1 element,
    // wave = 16 elements. B*4 threads -> 256 blocks -> 1 wave/SIMD (grid-
    // structural; more TLP impossible without raising demand).
    // Phase_x trig is HOISTED to loop top: it depends only on XC, and its
    // consumer sits ~300 FMA-cycles later (after L0+L1'), so the trans-pipe
    // latency is fully hidden instead of exposed mid-iteration.
    const int tid = blockIdx.x * blockDim.x + threadIdx.x;
    const int e   = tid >> 2;
    if (e >= B) return;
    const int sub = threadIdx.x & 3;
    const bool b2 = (sub & 1) != 0, b3 = (sub & 2) != 0;
    const float z2f = b2 ? -1.f : 1.f;
    const float z3f = b3 ? -1.f : 1.f;
    const float z23 = z2f * z3f;
    const bool is0 = (sub == 0), is1 = (sub == 1), is2 = (sub == 2);

    // Angles in REVOLUTIONS with -0.5 half-angle folded: stored = -rad/(4*pi).
    const float REVC = -0.07957747154594767f;   // -1/(4*pi)
    const float NQPI = -0.7853981633974483f;    // -pi/4

    // ---- one-time: 16 base Rot matrices (input-constant)
    float u00r[4][4], u00i[4][4], u01r[4][4], u01i[4][4];
    const float* PP[2] = { p1, p2 };
#pragma unroll
    for (int aI = 0; aI < 2; ++aI) {
        const float* pp = PP[aI];
#pragma unroll
        for (int l = 0; l < 2; ++l) {
            const int idx = aI*2 + l;
#pragma unroll
            for (int q = 0; q < 4; ++q) {
                float phi = pp[l*12 + q*3 + 0];
                float tht = pp[l*12 + q*3 + 1];
                float omg = pp[l*12 + q*3 + 2];
                float st, ct; sincosf(0.5f*tht, &st, &ct);
                float sA, cA, sB, cB;
                sincosf(0.5f*(phi + omg), &sA, &cA);
                sincosf(0.5f*(phi - omg), &sB, &cB);
                u00r[idx][q] = rfl( cA*ct); u00i[idx][q] = rfl(-sA*ct);
                u01r[idx][q] = rfl(-cB*st); u01i[idx][q] = rfl(-sB*st);
            }
        }
    }

    // ---- per-gate scalar coefficients {dr, di, orr, oi}, z2/z3 parts folded.
    // gates 0-3: L0 q0..q3; 4-7: L1' g0..g3 (det-1, sigma on dr&oi);
    // 8-11: L2 g0..g3 (det+1, sigma on di&orr); 12-15: L3 g0..g3.
    // Chain-sign (eps0/eps1) parts applied at call sites via negation.
    float cdr[16], cdi[16], cor_[16], coi[16];
    {
        const float f0[4] = {1.f, 1.f, z2f, z3f};          // L0 sigma: n0, n1, z2, z3
#pragma unroll
        for (int q = 0; q < 4; ++q) {
            cdr[q]  = u00r[0][q];
            cdi[q]  = f0[q]*u00i[0][q];
            cor_[q] = f0[q]*u01r[0][q];
            coi[q]  = u01i[0][q];
        }
        const float f1a[4] = {z23, 1.f, z2f, z23};         // L1' sigma z-parts
#pragma unroll
        for (int q = 0; q < 4; ++q) {
            float ar = u00r[1][q] - u01r[1][q];
            float ai = u00i[1][q] + u01i[1][q];
            float br = u00r[1][q] + u01r[1][q];
            float bi = u01i[1][q] - u00i[1][q];
            cdr[4+q]  = f1a[q]*ar;
            cdi[4+q]  = ai;
            cor_[4+q] = br;
            coi[4+q]  = f1a[q]*bi;
        }
        const float f2a[4] = {z23, z2f, z3f, 1.f};         // L2 sigma z-parts
#pragma unroll
        for (int q = 0; q < 4; ++q) {
            cdr[8+q]  = u00r[2][q];
            cdi[8+q]  = f2a[q]*u00i[2][q];
            cor_[8+q] = f2a[q]*u01r[2][q];
            coi[8+q]  = u01i[2][q];
        }
        const float f3a[4] = {z23, z3f, 1.f, 1.f};         // L3 sigma z-parts
#pragma unroll
        for (int q = 0; q < 4; ++q) {
            cdr[12+q]  = u00r[3][q];
            cdi[12+q]  = f3a[q]*u00i[3][q];
            cor_[12+q] = f3a[q]*u01r[3][q];
            coi[12+q]  = u01i[3][q];
        }
    }

    // ---- KAN cubic coeffs (lane 'sub' = input dim); REVC folded.
    float kQ0[7], kQ1[7], kQ2[7], kQ3[7], kBW[7];
#pragma unroll
    for (int r = 0; r < 7; ++r) {
        float sw0 = ksw[r*16 + sub*4 + 0], sw1 = ksw[r*16 + sub*4 + 1];
        float sw2 = ksw[r*16 + sub*4 + 2], sw3 = ksw[r*16 + sub*4 + 3];
        const float f = REVC / 48.0f;
        kQ0[r] = f * (sw0 + 23.f*sw1 + 23.f*sw2 + sw3);
        kQ1[r] = f * (-3.f*sw0 - 15.f*sw1 + 15.f*sw2 + 3.f*sw3);
        kQ2[r] = f * (3.f*sw0 - 3.f*sw1 - 3.f*sw2 + 3.f*sw3);
        kQ3[r] = f * (-sw0 + 3.f*sw1 - 3.f*sw2 + sw3);
        kBW[r] = REVC * kbw[r*4 + sub];
    }
    const int pr0[3] = {0, 1, 3}, pr1[3] = {4, 2, 6};
    v2 Q0p[3], Q1p[3], Q2p[3], Q3p[3], BWp[3];
#pragma unroll
    for (int j = 0; j < 3; ++j) {
        Q0p[j] = (v2){kQ0[pr0[j]], kQ0[pr1[j]]};
        Q1p[j] = (v2){kQ1[pr0[j]], kQ1[pr1[j]]};
        Q2p[j] = (v2){kQ2[pr0[j]], kQ2[pr1[j]]};
        Q3p[j] = (v2){kQ3[pr0[j]], kQ3[pr1[j]]};
        BWp[j] = (v2){kBW[pr0[j]], kBW[pr1[j]]};
    }

    // measurement residual sign + /256 (derivation in measurement block)
    const float SCL = (is0 ? z3f : z2f) * (1.0f/256.0f);
    const float zNQ3  = z3f * NQPI;
    const float zNQ23 = z23 * NQPI;

    // ---- per-element state
    v2 H04, H12, H36;
    float H5;
    const float4* inp4 = (const float4*)inputs;
    H04 = (v2){REVC*initial_t[e*7+0], REVC*initial_t[e*7+4]};
    H12 = (v2){REVC*initial_t[e*7+1], REVC*initial_t[e*7+2]};
    H36 = (v2){REVC*initial_t[e*7+3], REVC*initial_t[e*7+6]};
    H5  = REVC*initial_t[e*7+5];
    const long BASE = (long)e * S;
    float4 XC = inp4[BASE];

    float XK = 0.f;
    v2 a00, a01, a10, a11;   // a[n0][n1]

#pragma unroll 1
    for (int t = 0; t < S; ++t) {
        const int tn = (t + 1 < S) ? t + 1 : S - 1;
        float4 XN = inp4[BASE + tn];

        // ---- fm(hidden) on |0000>: sig(a,b) = c + e1*d + e0*(w0 + e1*w1)
        {
            float c_ = z2f*H12.y;
            c_ = fmaf(z3f, H36.x, c_);
            c_ = fmaf(z23, H36.y, c_);
            float d_ = fmaf(z2f, H5, H12.x);
            float w0 = H04.x, w1 = H04.y;
            float pd = c_ + d_, qd = c_ - d_;
            float rw = w0 + w1, sw = w0 - w1;
            float s00,c00,s01,c01,s10,c10,s11,c11;
            fsincos(pd + rw, &s00, &c00);
            fsincos(qd + sw, &s01, &c01);
            fsincos(pd - rw, &s10, &c10);
            fsincos(qd - sw, &s11, &c11);
            a00 = (v2){c00, s00}; a01 = (v2){c01, s01};
            a10 = (v2){c10, s10}; a11 = (v2){c11, s11};
        }

        // ---- Phase_x trig HOISTED: depends only on XC; consumer is ~300
        //      FMA-cycles away (after L0+L1'), so trans latency fully hides.
        v2 pc00, pc01, pc10, pc11;   // {cos, sin} per chain
        {
            float hx0 = REVC*XC.x, hx1 = REVC*XC.y;
            float hx2 = REVC*XC.z, hx3 = REVC*XC.w;
            float u0 = fmaf(4.f, hx0, 1.f);
            float u1 = fmaf(4.f, hx1, 1.f);
            float u2 = fmaf(4.f, hx2, 1.f);
            float u3 = fmaf(4.f, hx3, 1.f);
            float h4r = u0*u1, h5r = u1*u2, h6r = u2*u3;
            float c2 = z2f*hx1;
            c2 = fmaf(z3f, hx2, c2);
            c2 = fmaf(zNQ23, h5r, c2);
            float d2 = fmaf(zNQ3, h6r, hx3);
            float w2 = fmaf(zNQ3, h4r, z23*hx0);
            float p2 = c2 + d2, q2v = c2 - d2;
            float ps, pc, qs, qc, rs, rc, ss_, sc;
            fsincos(p2 + w2,  &ps, &pc);
            fsincos(q2v + w2, &qs, &qc);
            fsincos(p2 - w2,  &rs, &rc);
            fsincos(q2v - w2, &ss_, &sc);
            pc00 = (v2){pc, ps}; pc01 = (v2){qc, qs};
            pc10 = (v2){rc, rs}; pc11 = (v2){sc, ss_};
        }

        // ======== L0: ansatz1 layer1 ========
        {   // q0: n0-pair; eps0 on (di,orr)
            v2 n00 = gup_s(a00, a10, cdr[0],  cdi[0],  cor_[0], coi[0]);
            v2 n10 = gup_s(a10, a00, cdr[0], -cdi[0], -cor_[0], coi[0]);
            v2 n01 = gup_s(a01, a11, cdr[0],  cdi[0],  cor_[0], coi[0]);
            v2 n11 = gup_s(a11, a01, cdr[0], -cdi[0], -cor_[0], coi[0]);
            a00=n00; a10=n10; a01=n01; a11=n11;
        }
        {   // q1: n1-pair; eps1 on (di,orr)
            v2 n00 = gup_s(a00, a01, cdr[1],  cdi[1],  cor_[1], coi[1]);
            v2 n01 = gup_s(a01, a00, cdr[1], -cdi[1], -cor_[1], coi[1]);
            v2 n10 = gup_s(a10, a11, cdr[1],  cdi[1],  cor_[1], coi[1]);
            v2 n11 = gup_s(a11, a10, cdr[1], -cdi[1], -cor_[1], coi[1]);
            a00=n00; a01=n01; a10=n10; a11=n11;
        }
        // q2: lx1 self; z2 in consts
        a00 = gup_s(a00, lx1v(a00), cdr[2], cdi[2], cor_[2], coi[2]);
        a01 = gup_s(a01, lx1v(a01), cdr[2], cdi[2], cor_[2], coi[2]);
        a10 = gup_s(a10, lx1v(a10), cdr[2], cdi[2], cor_[2], coi[2]);
        a11 = gup_s(a11, lx1v(a11), cdr[2], cdi[2], cor_[2], coi[2]);
        // q3: lx2 self; z3 in consts
        a00 = gup_s(a00, lx2v(a00), cdr[3], cdi[3], cor_[3], coi[3]);
        a01 = gup_s(a01, lx2v(a01), cdr[3], cdi[3], cor_[3], coi[3]);
        a10 = gup_s(a10, lx2v(a10), cdr[3], cdi[3], cor_[3], coi[3]);
        a11 = gup_s(a11, lx2v(a11), cdr[3], cdi[3], cor_[3], coi[3]);

        // ======== L1': H-folded ansatz1 layer2 (det -1; sigma on dr&oi) ========
        {   // g0: mask {n0,n1}: cross-pair; eps1 on (dr,oi)
            v2 n00 = gup_s(a00, a11,  cdr[4], cdi[4], cor_[4],  coi[4]);
            v2 n01 = gup_s(a01, a10, -cdr[4], cdi[4], cor_[4], -coi[4]);
            v2 n10 = gup_s(a10, a01,  cdr[4], cdi[4], cor_[4],  coi[4]);
            v2 n11 = gup_s(a11, a00, -cdr[4], cdi[4], cor_[4], -coi[4]);
            a00=n00; a01=n01; a10=n10; a11=n11;
        }
        {   // g1: mask {n1,n2}: n1-pair + lx1; eps0*eps1 on (dr,oi)
            v2 p00 = lx1v(a01), p01 = lx1v(a00), p10 = lx1v(a11), p11 = lx1v(a10);
            v2 n00 = gup_s(a00, p00,  cdr[5], cdi[5], cor_[5],  coi[5]);
            v2 n01 = gup_s(a01, p01, -cdr[5], cdi[5], cor_[5], -coi[5]);
            v2 n10 = gup_s(a10, p10, -cdr[5], cdi[5], cor_[5], -coi[5]);
            v2 n11 = gup_s(a11, p11,  cdr[5], cdi[5], cor_[5],  coi[5]);
            a00=n00; a01=n01; a10=n10; a11=n11;
        }
        // g2: mask {n2,n3}: x3 self; eps0*eps1 on (dr,oi)
        a00 = gup_s(a00, x3v(a00),  cdr[6], cdi[6], cor_[6],  coi[6]);
        a01 = gup_s(a01, x3v(a01), -cdr[6], cdi[6], cor_[6], -coi[6]);
        a10 = gup_s(a10, x3v(a10), -cdr[6], cdi[6], cor_[6], -coi[6]);
        a11 = gup_s(a11, x3v(a11),  cdr[6], cdi[6], cor_[6],  coi[6]);
        {   // g3: mask {n0,n1,n3}: cross-pair + lx2; eps0*eps1 on (dr,oi)
            v2 p00 = lx2v(a11), p01 = lx2v(a10), p10 = lx2v(a01), p11 = lx2v(a00);
            v2 n00 = gup_s(a00, p00,  cdr[7], cdi[7], cor_[7],  coi[7]);
            v2 n01 = gup_s(a01, p01, -cdr[7], cdi[7], cor_[7], -coi[7]);
            v2 n10 = gup_s(a10, p10, -cdr[7], cdi[7], cor_[7], -coi[7]);
            v2 n11 = gup_s(a11, p11,  cdr[7], cdi[7], cor_[7],  coi[7]);
            a00=n00; a01=n01; a10=n10; a11=n11;
        }

        // ======== Phase_x apply (pairs precomputed at loop top) ========
        a00 = prot(a00, pc00);
        a01 = prot(a01, pc01);
        a10 = prot(a10, pc10);
        a11 = prot(a11, pc11);

        // ======== L2: ansatz2 layer1 (det +1; sigma on di&orr) ========
        {   // g0: mask {n0}: n0-pair; eps0 on (di,orr)
            v2 n00 = gup_s(a00, a10, cdr[8],  cdi[8],  cor_[8], coi[8]);
            v2 n10 = gup_s(a10, a00, cdr[8], -cdi[8], -cor_[8], coi[8]);
            v2 n01 = gup_s(a01, a11, cdr[8],  cdi[8],  cor_[8], coi[8]);
            v2 n11 = gup_s(a11, a01, cdr[8], -cdi[8], -cor_[8], coi[8]);
            a00=n00; a10=n10; a01=n01; a11=n11;
        }
        {   // g1: mask {n0,n2}: n0-pair + lx1; no chain signs (z2 in consts)
            v2 p00 = lx1v(a10), p10 = lx1v(a00), p01 = lx1v(a11), p11 = lx1v(a01);
            v2 n00 = gup_s(a00, p00, cdr[9], cdi[9], cor_[9], coi[9]);
            v2 n10 = gup_s(a10, p10, cdr[9], cdi[9], cor_[9], coi[9]);
            v2 n01 = gup_s(a01, p01, cdr[9], cdi[9], cor_[9], coi[9]);
            v2 n11 = gup_s(a11, p11, cdr[9], cdi[9], cor_[9], coi[9]);
            a00=n00; a10=n10; a01=n01; a11=n11;
        }
        {   // g2: mask {n0,n3}: n0-pair + lx2; no chain signs (z3 in consts)
            v2 p00 = lx2v(a10), p10 = lx2v(a00), p01 = lx2v(a11), p11 = lx2v(a01);
            v2 n00 = gup_s(a00, p00, cdr[10], cdi[10], cor_[10], coi[10]);
            v2 n10 = gup_s(a10, p10, cdr[10], cdi[10], cor_[10], coi[10]);
            v2 n01 = gup_s(a01, p01, cdr[10], cdi[10], cor_[10], coi[10]);
            v2 n11 = gup_s(a11, p11, cdr[10], cdi[10], cor_[10], coi[10]);
            a00=n00; a10=n10; a01=n01; a11=n11;
        }
        {   // g3: mask {n1}: n1-pair; eps1 on (di,orr)
            v2 n00 = gup_s(a00, a01, cdr[11],  cdi[11],  cor_[11], coi[11]);
            v2 n01 = gup_s(a01, a00, cdr[11], -cdi[11], -cor_[11], coi[11]);
            v2 n10 = gup_s(a10, a11, cdr[11],  cdi[11],  cor_[11], coi[11]);
            v2 n11 = gup_s(a11, a10, cdr[11], -cdi[11], -cor_[11], coi[11]);
            a00=n00; a01=n01; a10=n10; a11=n11;
        }

        // ======== L3: ansatz2 layer2 (det +1; sigma on di&orr) ========
        // g0: mask {n2}: lx1 self; eps1 on (di,orr), z23 in consts
        a00 = gup_s(a00, lx1v(a00), cdr[12],  cdi[12],  cor_[12], coi[12]);
        a01 = gup_s(a01, lx1v(a01), cdr[12], -cdi[12], -cor_[12], coi[12]);
        a10 = gup_s(a10, lx1v(a10), cdr[12],  cdi[12],  cor_[12], coi[12]);
        a11 = gup_s(a11, lx1v(a11), cdr[12], -cdi[12], -cor_[12], coi[12]);
        // g1: mask {n2,n3}: x3 self; eps0 on (di,orr), z3 in consts
        a00 = gup_s(a00, x3v(a00), cdr[13],  cdi[13],  cor_[13], coi[13]);
        a01 = gup_s(a01, x3v(a01), cdr[13],  cdi[13],  cor_[13], coi[13]);
        a10 = gup_s(a10, x3v(a10), cdr[13], -cdi[13], -cor_[13], coi[13]);
        a11 = gup_s(a11, x3v(a11), cdr[13], -cdi[13], -cor_[13], coi[13]);
        {   // g2: mask {n0,n1,n3}: cross-pair + lx2; eps0 on (di,orr)
            v2 p00 = lx2v(a11), p01 = lx2v(a10), p10 = lx2v(a01), p11 = lx2v(a00);
            v2 n00 = gup_s(a00, p00, cdr[14],  cdi[14],  cor_[14], coi[14]);
            v2 n01 = gup_s(a01, p01, cdr[14],  cdi[14],  cor_[14], coi[14]);
            v2 n10 = gup_s(a10, p10, cdr[14], -cdi[14], -cor_[14], coi[14]);
            v2 n11 = gup_s(a11, p11, cdr[14], -cdi[14], -cor_[14], coi[14]);
            a00=n00; a01=n01; a10=n10; a11=n11;
        }
        {   // g3: mask {n1,n2}: n1-pair + lx1; eps0*eps1 on (di,orr)
            v2 p00 = lx1v(a01), p01 = lx1v(a00), p10 = lx1v(a11), p11 = lx1v(a10);
            v2 n00 = gup_s(a00, p00, cdr[15],  cdi[15],  cor_[15], coi[15]);
            v2 n01 = gup_s(a01, p01, cdr[15], -cdi[15], -cor_[15], coi[15]);
            v2 n10 = gup_s(a10, p10, cdr[15], -cdi[15], -cor_[15], coi[15]);
            v2 n11 = gup_s(a11, p11, cdr[15],  cdi[15],  cor_[15], coi[15]);
            a00=n00; a01=n01; a10=n10; a11=n11;
        }

        // ---- measurement (Walsh over n0,n1 in-register; n2,n3 quad DPP)
        // EV0 = sum(-1)^{n0+n1+n3}p, EV1 = sum(-1)^{n0+n1+n2}p,
        // EV2 = sum(-1)^{n1+n2}p,    EV3 = sum(-1)^{n0+n2}p   (probs x256)
        {
            float m00 = fmaf(a00.y, a00.y, a00.x*a00.x);
            float m01 = fmaf(a01.y, a01.y, a01.x*a01.x);
            float m10 = fmaf(a10.y, a10.y, a10.x*a10.x);
            float m11 = fmaf(a11.y, a11.y, a11.x*a11.x);
            float g_ = m00 - m01, h_ = m10 - m11;
            float dl01 = g_ - h_;                         // (-1)^{n0^n1}
            float sn1  = g_ + h_;                         // (-1)^{n1}
            float dn0  = (m00 + m01) - (m10 + m11);       // (-1)^{n0}
            float l1a = lx1(dl01);
            float up = dl01 + l1a;
            float um = dl01 - l1a;
            float t0 = up - lx2(up);                      // z3f * EV0*256
            float t1 = um + lx2(um);                      // z2f * EV1*256
            float vm = sn1 - lx1(sn1);
            float t2 = vm + lx2(vm);                      // z2f * EV2*256
            float wm = dn0 - lx1(dn0);
            float t3 = wm + lx2(wm);                      // z2f * EV3*256
            float pre = is0 ? t0 : (is1 ? t1 : (is2 ? t2 : t3));
            XK = pre * SCL;
        }

        // ---- KAN (packed pairs): lane sub = input dim; quad-reduce sums dims
        {
            float xk = XK;
            float eneg = __builtin_amdgcn_exp2f(xk * -1.44269504088896f);
            float silu = xk * __builtin_amdgcn_rcpf(1.0f + eneg);
            v2 xs = (v2){xk, xk}, ss = (v2){silu, silu};
            v2 op[3];
#pragma unroll
            for (int k = 0; k < 3; ++k) {
                v2 o = __builtin_elementwise_fma(Q3p[k], xs, Q2p[k]);
                o = __builtin_elementwise_fma(o, xs, Q1p[k]);
                o = __builtin_elementwise_fma(o, xs, Q0p[k]);
                o = __builtin_elementwise_fma(BWp[k], ss, o);
                o = o + (v2){lx1(o.x), lx1(o.y)};
                o = o + (v2){lx2(o.x), lx2(o.y)};
                op[k] = o;
            }
            {   // scalar r=5
                float o = fmaf(kQ3[5], xk, kQ2[5]);
                o = fmaf(o, xk, kQ1[5]);
                o = fmaf(o, xk, kQ0[5]);
                o = fmaf(kBW[5], silu, o);
                o += lx1(o); o += lx2(o);
                H5 = o;
            }
            H04 = op[0]; H12 = op[1]; H36 = op[2];
            XC = XN;
        }
    }

    // ---- classifier head: quad lanes hold ev0..ev3 per element
    {
        float xk  = XK;
        float ev1 = qperm<0x55>(xk);
        float ev2 = qperm<0xAA>(xk);
        float ev3 = qperm<0xFF>(xk);
        if (is0) {
            float acc = cb2[0];
#pragma unroll
            for (int i = 0; i < 16; ++i) {
                float h = cb1[i] + w1[i*4+0]*xk + w1[i*4+1]*ev1
                        + w1[i*4+2]*ev2 + w1[i*4+3]*ev3;
                h = fmaxf(h, 0.0f);
                acc += w2[i]*h;
            }
            out[e] = acc;
        }
    }
}

extern "C" void kernel_launch(void* const* d_in, const int* in_sizes, int n_in,
                              void* d_out, int out_size, void* d_ws, size_t ws_size,
                              hipStream_t stream) {
    const float* inputs    = (const float*)d_in[0];
    const float* initial_t = (const float*)d_in[1];
    const float* p1        = (const float*)d_in[2];
    const float* p2        = (const float*)d_in[3];
    const float* kbw       = (const float*)d_in[4];
    const float* ksw       = (const float*)d_in[5];
    const float* w1        = (const float*)d_in[6];
    const float* cb1       = (const float*)d_in[7];
    const float* w2        = (const float*)d_in[8];
    const float* cb2       = (const float*)d_in[9];

    const int B = in_sizes[1] / 7;            // 16384
    const int S = in_sizes[0] / (B * 4);      // 256

    const int threads = B * 4;                // 4 lanes/element, 1 element/thread
    const int block = 256;
    const int grid = (threads + block - 1) / block;   // 256 blocks -> 1 wave/SIMD

    qrnn_kernel<<<grid, block, 0, stream>>>(inputs, initial_t, p1, p2, kbw, ksw,
                                            w1, cb1, w2, cb2, (float*)d_out, B, S);
}